// Round 4
// baseline (275.098 us; speedup 1.0000x reference)
//
// Swin block fwd, MI355X gfx950. Round 4: FUSED attn+MLP per window (kills 100MB x2w roundtrip),
// coalesced fp32 epilogue via LDS restage, shortcut kept in registers.
// K0: weight transposes fp32->bf16 (K-contiguous for B-fragments)
// K1: per-window fused LN1 + shift-gather + QKV + attn(softmax/rpb/mask) + proj
//     + LN2 + MLP(gelu tanh-form) + both residuals -> out (fp32, original layout)
#include <hip/hip_runtime.h>
#include <math.h>

typedef __attribute__((ext_vector_type(8))) short bf16x8;
typedef __attribute__((ext_vector_type(4))) float f32x4;

#define DEVI __device__ __forceinline__

DEVI float b2f(unsigned int u){ union{unsigned int i; float f;} c; c.i = u<<16; return c.f; }
DEVI unsigned short f2b(float f){
  union{float f; unsigned int i;} c; c.f = f;
  unsigned int r = c.i + 0x7fffu + ((c.i>>16)&1u);
  return (unsigned short)(r>>16);
}
DEVI unsigned int pack2(float a, float b){
  return (unsigned int)f2b(a) | ((unsigned int)f2b(b)<<16);
}
DEVI f32x4 mfma16(bf16x8 a, bf16x8 b, f32x4 c){
  return __builtin_amdgcn_mfma_f32_16x16x32_bf16(a, b, c, 0, 0, 0);
}
// tanh-form GELU: max abs err vs exact ~3e-3
DEVI float gelu_fast(float u){
  const float y = 0.7978845608028654f*(u + 0.044715f*u*u*u);
  const float t = __expf(2.f*y);
  const float th = 1.f - 2.f/(t + 1.f);
  return 0.5f*u*(1.f + th);
}
// XOR swizzles: fold row bits into byte-offset bits[4:6]
DEVI int swzA(int row, int byi){ return row*256 + (byi ^ ((row&7)<<4)); }      // 64x128 bf16
DEVI int swzQ(int row, int byi){ return row*64  + (byi ^ (((row>>1)&3)<<4)); } // 64x32  bf16
DEVI int swzP(int row, int byi){ return row*128 + (byi ^ ((row&7)<<4)); }      // 64x64 / 32x64
DEVI int swzH(int row, int byi){ return row*512 + (byi ^ ((row&7)<<4)); }      // 64x256 bf16 / 64x128 f32

// ---------------- K0: weight transpose fp32 -> bf16, [N][K] layout ----------------
__global__ void k_prep(const float* __restrict__ qkvw, const float* __restrict__ projw,
                       const float* __restrict__ w1,   const float* __restrict__ w2,
                       ushort* __restrict__ qkvT, ushort* __restrict__ projT,
                       ushort* __restrict__ w1T,  ushort* __restrict__ w2T)
{
  const int id = blockIdx.x*256 + threadIdx.x;                 // 0..65535
  if (id < 49152){ const int k=id/384, c=id%384; qkvT[c*128+k] = f2b(qkvw[id]); } // (128,384)->(384,128)
  if (id < 16384){ const int k=id>>7, c=id&127;  projT[c*128+k] = f2b(projw[id]); } // (128,128)T
  { const int k=id>>9, c=id&511; w1T[c*128+k] = f2b(w1[id]); }  // (128,512)->(512,128)
  { const int k=id>>7, c=id&127; w2T[c*512+k] = f2b(w2[id]); }  // (512,128)->(128,512)
}

// ---------------- K1: fully fused Swin block per window ----------------
__global__ __launch_bounds__(256,2) void k_fused(
    const float*  __restrict__ x,
    const float*  __restrict__ g1, const float* __restrict__ be1,
    const ushort* __restrict__ qkvT, const float* __restrict__ qkvb,
    const ushort* __restrict__ projT, const float* __restrict__ projb,
    const float*  __restrict__ rpbt,
    const float*  __restrict__ g2, const float* __restrict__ be2,
    const ushort* __restrict__ w1T, const float* __restrict__ bb1,
    const ushort* __restrict__ w2T, const float* __restrict__ bb2,
    float* __restrict__ outp)
{
  __shared__ __align__(16) char smem[65536];
  const int tid  = threadIdx.x;
  const int wave = tid>>6, lane = tid&63;
  const int l15 = lane&15, l4 = lane>>4;
  const int wid = blockIdx.x;
  const int b   = wid>>6, wim = wid&63;
  const int wh  = wim>>3, wv = wim&7;

  char* const smA  = smem;                       // 16 KB: LN1 tile / attn-O / LN2 tile
  char* const smHd = smem + 16384 + wave*12288;  // per-head 12 KB (attn phases only)
  char* const smQ  = smHd;                       // 4 KB (64x32)
  char* const smK  = smHd + 4096;                // 4 KB
  char* const smVT = smHd + 8192;                // 4 KB (32x64, V transposed)
  char* const smP  = smHd;                       // 8 KB, overlays Q+K after scores
  char* const smRaw = smem + 16384;              // 16 KB: proj-out bf16 (post-attn; head mem dead)
  char* const smH2  = smem + 32768;              // 32 KB: MLP hidden / OA fp32 stage (head mem dead)

  const f32x4 Z = {0.f,0.f,0.f,0.f};

  // per-thread row mapping used by phases 1 / LN2 / epilogue
  const int t_row = tid>>2;
  const int cg    = (tid&3)*32;
  const int ti_r = t_row>>3, tj_r = t_row&7;
  const int ho_r = (wh*8+ti_r+4)&63, wo_r = (wv*8+tj_r+4)&63;
  const size_t growbase = ((size_t)(b*4096 + ho_r*64 + wo_r))*128;

  float xraw[32];   // raw (shifted-gathered) x row-chunk: the attn shortcut

  // ---- Phase 1: gather (roll -4,-4) + LayerNorm1 -> smA (bf16, swizzled) ----
  {
    const float* src = x + growbase + cg;
    #pragma unroll
    for(int q=0;q<8;q++){
      const float4 f4 = *(const float4*)(src + q*4);
      xraw[q*4+0]=f4.x; xraw[q*4+1]=f4.y; xraw[q*4+2]=f4.z; xraw[q*4+3]=f4.w;
    }
    float s=0.f, ss=0.f;
    #pragma unroll
    for(int e=0;e<32;e++){ s+=xraw[e]; ss+=xraw[e]*xraw[e]; }
    s += __shfl_xor(s,1); ss += __shfl_xor(ss,1);
    s += __shfl_xor(s,2); ss += __shfl_xor(ss,2);
    const float mean = s*(1.f/128.f);
    const float varv = fmaxf(ss*(1.f/128.f) - mean*mean, 0.f);
    const float rstd = rsqrtf(varv + 1e-5f);
    #pragma unroll
    for(int q=0;q<4;q++){
      const float4 ga = *(const float4*)(g1 +cg+q*8);
      const float4 gb = *(const float4*)(g1 +cg+q*8+4);
      const float4 ba = *(const float4*)(be1+cg+q*8);
      const float4 bb = *(const float4*)(be1+cg+q*8+4);
      const float* vp = xraw + q*8;
      uint4 pk;
      pk.x = pack2((vp[0]-mean)*rstd*ga.x+ba.x, (vp[1]-mean)*rstd*ga.y+ba.y);
      pk.y = pack2((vp[2]-mean)*rstd*ga.z+ba.z, (vp[3]-mean)*rstd*ga.w+ba.w);
      pk.z = pack2((vp[4]-mean)*rstd*gb.x+bb.x, (vp[5]-mean)*rstd*gb.y+bb.y);
      pk.w = pack2((vp[6]-mean)*rstd*gb.z+bb.z, (vp[7]-mean)*rstd*gb.w+bb.w);
      *(uint4*)(smA + swzA(t_row, cg*2 + q*16)) = pk;
    }
  }
  __syncthreads();

  // ---- Phase 2: QKV for this wave's head (Q scaled, V stored transposed) ----
  const int headc = wave*32;
  {
    #pragma unroll
    for(int s3=0;s3<3;s3++){
      f32x4 acc[4][2];
      #pragma unroll
      for(int rt=0;rt<4;rt++){ acc[rt][0]=Z; acc[rt][1]=Z; }
      const ushort* wbase = qkvT + (size_t)(s3*128 + headc)*128;
      bf16x8 bfr[2][4];
      #pragma unroll
      for(int ct=0;ct<2;ct++)
        #pragma unroll
        for(int kk=0;kk<4;kk++)
          bfr[ct][kk] = *(const bf16x8*)(wbase + (ct*16+l15)*128 + kk*32 + l4*8);
      #pragma unroll
      for(int kk=0;kk<4;kk++){
        bf16x8 afr[4];
        #pragma unroll
        for(int rt=0;rt<4;rt++)
          afr[rt] = *(const bf16x8*)(smA + swzA(rt*16+l15, kk*64 + l4*16));
        #pragma unroll
        for(int rt=0;rt<4;rt++)
          #pragma unroll
          for(int ct=0;ct<2;ct++)
            acc[rt][ct] = mfma16(afr[rt], bfr[ct][kk], acc[rt][ct]);
      }
      #pragma unroll
      for(int ct=0;ct<2;ct++){
        const int hd = ct*16 + l15;
        const float bias = qkvb[s3*128 + headc + hd];
        #pragma unroll
        for(int rt=0;rt<4;rt++){
          const int t0 = rt*16 + l4*4;
          if (s3==2){
            uint2 pk;
            pk.x = pack2(acc[rt][ct][0]+bias, acc[rt][ct][1]+bias);
            pk.y = pack2(acc[rt][ct][2]+bias, acc[rt][ct][3]+bias);
            *(uint2*)(smVT + swzP(hd, t0*2)) = pk;       // V^T[hd][tok..tok+4)
          } else {
            char* const dst = (s3==0) ? smQ : smK;
            const float sc = (s3==0) ? 0.17677669529663687f : 1.f;
            #pragma unroll
            for(int j=0;j<4;j++)
              *(ushort*)(dst + swzQ(t0+j, hd*2)) = f2b((acc[rt][ct][j]+bias)*sc);
          }
        }
      }
    }
  }
  __syncthreads();  // all waves done reading smA (it becomes O below)

  // ---- Phase 3: scores (Q K^T) + rpb + shift-mask + softmax -> P bf16 ----
  {
    f32x4 S[4][4];
    bf16x8 qfr[4], kfr[4];
    #pragma unroll
    for(int i=0;i<4;i++) qfr[i] = *(const bf16x8*)(smQ + swzQ(i*16+l15, l4*16));
    #pragma unroll
    for(int i=0;i<4;i++) kfr[i] = *(const bf16x8*)(smK + swzQ(i*16+l15, l4*16));
    #pragma unroll
    for(int rt=0;rt<4;rt++)
      #pragma unroll
      for(int ct=0;ct<4;ct++)
        S[rt][ct] = mfma16(qfr[rt], kfr[ct], Z);

    const bool edge = (wh==7) || (wv==7);
    #pragma unroll
    for(int ct=0;ct<4;ct++){
      const int m = ct*16 + l15;
      const int im = m>>3, jm = m&7;
      const int regm = ((wh<7)?0:((im<4)?1:2))*3 + ((wv<7)?0:((jm<4)?1:2));
      #pragma unroll
      for(int rt=0;rt<4;rt++)
        #pragma unroll
        for(int j=0;j<4;j++){
          const int n = rt*16 + l4*4 + j;
          const int in_ = n>>3, jn = n&7;
          float add = rpbt[((in_-im+7)*15 + (jn-jm+7))*4 + wave];
          if (edge){
            const int regn = ((wh<7)?0:((in_<4)?1:2))*3 + ((wv<7)?0:((jn<4)?1:2));
            if (regn != regm) add -= 100.f;
          }
          S[rt][ct][j] += add;
        }
    }
    #pragma unroll
    for(int rt=0;rt<4;rt++)
      #pragma unroll
      for(int j=0;j<4;j++){
        float mx = fmaxf(fmaxf(S[rt][0][j],S[rt][1][j]), fmaxf(S[rt][2][j],S[rt][3][j]));
        mx = fmaxf(mx, __shfl_xor(mx,1));
        mx = fmaxf(mx, __shfl_xor(mx,2));
        mx = fmaxf(mx, __shfl_xor(mx,4));
        mx = fmaxf(mx, __shfl_xor(mx,8));
        float sm = 0.f;
        #pragma unroll
        for(int ct=0;ct<4;ct++){ const float e = __expf(S[rt][ct][j]-mx); S[rt][ct][j]=e; sm+=e; }
        sm += __shfl_xor(sm,1);
        sm += __shfl_xor(sm,2);
        sm += __shfl_xor(sm,4);
        sm += __shfl_xor(sm,8);
        const float inv = 1.f/sm;
        #pragma unroll
        for(int ct=0;ct<4;ct++) S[rt][ct][j] *= inv;
      }
    #pragma unroll
    for(int rt=0;rt<4;rt++)
      #pragma unroll
      for(int j=0;j<4;j++){
        const int n = rt*16 + l4*4 + j;
        #pragma unroll
        for(int ct=0;ct<4;ct++)
          *(ushort*)(smP + swzP(n, (ct*16+l15)*2)) = f2b(S[rt][ct][j]);
      }
  }

  // ---- Phase 4: O = P V -> smA (bf16 row-major, all heads) ----
  {
    f32x4 O[4][2];
    #pragma unroll
    for(int rt=0;rt<4;rt++){ O[rt][0]=Z; O[rt][1]=Z; }
    #pragma unroll
    for(int kk=0;kk<2;kk++){
      bf16x8 pfr[4], vfr[2];
      #pragma unroll
      for(int rt=0;rt<4;rt++)
        pfr[rt] = *(const bf16x8*)(smP + swzP(rt*16+l15, kk*64 + l4*16));
      #pragma unroll
      for(int ct=0;ct<2;ct++)
        vfr[ct] = *(const bf16x8*)(smVT + swzP(ct*16+l15, kk*64 + l4*16));
      #pragma unroll
      for(int rt=0;rt<4;rt++)
        #pragma unroll
        for(int ct=0;ct<2;ct++)
          O[rt][ct] = mfma16(pfr[rt], vfr[ct], O[rt][ct]);
    }
    #pragma unroll
    for(int rt=0;rt<4;rt++)
      #pragma unroll
      for(int ct=0;ct<2;ct++)
        #pragma unroll
        for(int j=0;j<4;j++){
          const int t = rt*16 + l4*4 + j;
          *(ushort*)(smA + swzA(t, (headc + ct*16 + l15)*2)) = f2b(O[rt][ct][j]);
        }
  }
  __syncthreads();   // all phase-4 LDS reads done; head area is now dead

  // ---- Phase 5: proj + bias -> smRaw (bf16, NO shortcut; shortcut lives in regs) ----
  {
    f32x4 PR[4][2];
    #pragma unroll
    for(int rt=0;rt<4;rt++){ PR[rt][0]=Z; PR[rt][1]=Z; }
    bf16x8 pb[2][4];
    #pragma unroll
    for(int ct=0;ct<2;ct++)
      #pragma unroll
      for(int kk=0;kk<4;kk++)
        pb[ct][kk] = *(const bf16x8*)(projT + (headc+ct*16+l15)*128 + kk*32 + l4*8);
    #pragma unroll
    for(int kk=0;kk<4;kk++){
      bf16x8 afr[4];
      #pragma unroll
      for(int rt=0;rt<4;rt++)
        afr[rt] = *(const bf16x8*)(smA + swzA(rt*16+l15, kk*64 + l4*16));
      #pragma unroll
      for(int rt=0;rt<4;rt++)
        #pragma unroll
        for(int ct=0;ct<2;ct++)
          PR[rt][ct] = mfma16(afr[rt], pb[ct][kk], PR[rt][ct]);
    }
    #pragma unroll
    for(int ct=0;ct<2;ct++){
      const int col = headc + ct*16 + l15;
      const float bias = projb[col];
      #pragma unroll
      for(int rt=0;rt<4;rt++)
        #pragma unroll
        for(int j=0;j<4;j++){
          const int t = rt*16 + l4*4 + j;
          *(ushort*)(smRaw + swzA(t, col*2)) = f2b(PR[rt][ct][j] + bias);
        }
    }
  }
  __syncthreads();

  // ---- Phase 6: x2 = xraw + projout (fp32, regs) ; LayerNorm2 -> smA ----
  // xraw[] becomes x2[] in place
  {
    #pragma unroll
    for(int q=0;q<4;q++){
      const uint4 pk = *(const uint4*)(smRaw + swzA(t_row, cg*2 + q*16));
      float* vp = xraw + q*8;
      vp[0]+=b2f(pk.x&0xffffu); vp[1]+=b2f(pk.x>>16);
      vp[2]+=b2f(pk.y&0xffffu); vp[3]+=b2f(pk.y>>16);
      vp[4]+=b2f(pk.z&0xffffu); vp[5]+=b2f(pk.z>>16);
      vp[6]+=b2f(pk.w&0xffffu); vp[7]+=b2f(pk.w>>16);
    }
    float s=0.f, ss=0.f;
    #pragma unroll
    for(int e=0;e<32;e++){ s+=xraw[e]; ss+=xraw[e]*xraw[e]; }
    s += __shfl_xor(s,1); ss += __shfl_xor(ss,1);
    s += __shfl_xor(s,2); ss += __shfl_xor(ss,2);
    const float mean = s*(1.f/128.f);
    const float varv = fmaxf(ss*(1.f/128.f) - mean*mean, 0.f);
    const float rstd = rsqrtf(varv + 1e-5f);
    #pragma unroll
    for(int q=0;q<4;q++){
      const float4 ga = *(const float4*)(g2 +cg+q*8);
      const float4 gb = *(const float4*)(g2 +cg+q*8+4);
      const float4 ba = *(const float4*)(be2+cg+q*8);
      const float4 bb = *(const float4*)(be2+cg+q*8+4);
      const float* vp = xraw + q*8;
      uint4 pk;
      pk.x = pack2((vp[0]-mean)*rstd*ga.x+ba.x, (vp[1]-mean)*rstd*ga.y+ba.y);
      pk.y = pack2((vp[2]-mean)*rstd*ga.z+ba.z, (vp[3]-mean)*rstd*ga.w+ba.w);
      pk.z = pack2((vp[4]-mean)*rstd*gb.x+bb.x, (vp[5]-mean)*rstd*gb.y+bb.y);
      pk.w = pack2((vp[6]-mean)*rstd*gb.z+bb.z, (vp[7]-mean)*rstd*gb.w+bb.w);
      *(uint4*)(smA + swzA(t_row, cg*2 + q*16)) = pk;
    }
  }
  __syncthreads();

  // ---- Phase 7: MLP (2 halves of hidden 512) ----
  f32x4 OA[4][2];
  #pragma unroll
  for(int rt=0;rt<4;rt++){ OA[rt][0]=Z; OA[rt][1]=Z; }

  #pragma unroll
  for(int ph=0; ph<2; ++ph){
    f32x4 HA[4][4];
    #pragma unroll
    for(int rt=0;rt<4;rt++)
      #pragma unroll
      for(int ct=0;ct<4;ct++) HA[rt][ct]=Z;
    const int c0 = ph*256 + wave*64;
    #pragma unroll
    for(int kk=0;kk<4;kk++){
      bf16x8 afr[4];
      #pragma unroll
      for(int rt=0;rt<4;rt++)
        afr[rt] = *(const bf16x8*)(smA + swzA(rt*16+l15, kk*64 + l4*16));
      bf16x8 bfr[4];
      #pragma unroll
      for(int ct=0;ct<4;ct++)
        bfr[ct] = *(const bf16x8*)(w1T + (size_t)(c0+ct*16+l15)*128 + kk*32 + l4*8);
      #pragma unroll
      for(int rt=0;rt<4;rt++)
        #pragma unroll
        for(int ct=0;ct<4;ct++)
          HA[rt][ct] = mfma16(afr[rt], bfr[ct], HA[rt][ct]);
    }
    if (ph==1) __syncthreads();   // WAR: all waves done reading smH2 half 0
    #pragma unroll
    for(int ct=0;ct<4;ct++){
      const int ch = wave*64 + ct*16 + l15;   // col within half [0,256)
      const float bias = bb1[ph*256 + ch];
      #pragma unroll
      for(int rt=0;rt<4;rt++)
        #pragma unroll
        for(int j=0;j<4;j++){
          const float u = HA[rt][ct][j] + bias;
          *(ushort*)(smH2 + swzH(rt*16+l4*4+j, ch*2)) = f2b(gelu_fast(u));
        }
    }
    __syncthreads();
    #pragma unroll
    for(int kk=0;kk<8;kk++){
      bf16x8 afr[4];
      #pragma unroll
      for(int rt=0;rt<4;rt++)
        afr[rt] = *(const bf16x8*)(smH2 + swzH(rt*16+l15, kk*64 + l4*16));
      bf16x8 bfr[2];
      #pragma unroll
      for(int ct=0;ct<2;ct++)
        bfr[ct] = *(const bf16x8*)(w2T + (size_t)(wave*32+ct*16+l15)*512 + ph*256 + kk*32 + l4*8);
      #pragma unroll
      for(int rt=0;rt<4;rt++)
        #pragma unroll
        for(int ct=0;ct<2;ct++)
          OA[rt][ct] = mfma16(afr[rt], bfr[ct], OA[rt][ct]);
    }
  }
  __syncthreads();   // all waves done reading smH2 (hidden half 1)

  // ---- Phase 8: stage OA fp32 into smH2 (64x128 f32, swizzled) ----
  #pragma unroll
  for(int ct=0;ct<2;ct++){
    const int col = wave*32 + ct*16 + l15;
    #pragma unroll
    for(int rt=0;rt<4;rt++)
      #pragma unroll
      for(int j=0;j<4;j++){
        const int t = rt*16 + l4*4 + j;
        *(float*)(smH2 + t*512 + ((col*4) ^ ((t&7)<<4))) = OA[rt][ct][j];
      }
  }
  __syncthreads();

  // ---- Phase 9: out = x2(regs) + bias2 + mlp_out, coalesced fp32 row stores ----
  {
    float* dst = outp + growbase + cg;
    #pragma unroll
    for(int q=0;q<8;q++){
      const f32x4 o4 = *(const f32x4*)(smH2 + t_row*512 + (((cg+q*4)*4) ^ ((t_row&7)<<4)));
      const float4 b4 = *(const float4*)(bb2 + cg + q*4);
      float4 r;
      r.x = o4[0] + b4.x + xraw[q*4+0];
      r.y = o4[1] + b4.y + xraw[q*4+1];
      r.z = o4[2] + b4.z + xraw[q*4+2];
      r.w = o4[3] + b4.w + xraw[q*4+3];
      *(float4*)(dst + q*4) = r;
    }
  }
}

extern "C" void kernel_launch(void* const* d_in, const int* in_sizes, int n_in,
                              void* d_out, int out_size, void* d_ws, size_t ws_size,
                              hipStream_t stream) {
  (void)in_sizes; (void)n_in; (void)out_size; (void)ws_size;
  const float* x     = (const float*)d_in[0];
  const float* n1g   = (const float*)d_in[1];
  const float* n1b   = (const float*)d_in[2];
  const float* qkvw  = (const float*)d_in[3];
  const float* qkvb  = (const float*)d_in[4];
  const float* projw = (const float*)d_in[5];
  const float* projb = (const float*)d_in[6];
  const float* rpbt  = (const float*)d_in[7];
  const float* n2g   = (const float*)d_in[8];
  const float* n2b   = (const float*)d_in[9];
  const float* w1    = (const float*)d_in[10];
  const float* b1    = (const float*)d_in[11];
  const float* w2    = (const float*)d_in[12];
  const float* b2    = (const float*)d_in[13];
  float* outp = (float*)d_out;

  ushort* ws    = (ushort*)d_ws;
  ushort* qkvT  = ws;                  // 49152
  ushort* projT = qkvT + 49152;        // 16384
  ushort* w1T   = projT + 16384;       // 65536
  ushort* w2T   = w1T + 65536;         // 65536   (total ws ~0.4 MB)

  k_prep<<<256, 256, 0, stream>>>(qkvw, projw, w1, w2, qkvT, projT, w1T, w2T);
  k_fused<<<2048, 256, 0, stream>>>(x, n1g, n1b, qkvT, qkvb, projT, projb, rpbt,
                                    n2g, n2b, w1T, b1, w2T, b2, outp);
}

// Round 5
// 269.030 us; speedup vs baseline: 1.0226x; 1.0226x over previous
//
// Swin block fwd, MI355X gfx950. Round 5: fragment-ordered weights (coalesced B-frag loads),
// split kernels (fusion lost), k_mlp single x2w read + coalesced fp32 epilogue.
#include <hip/hip_runtime.h>
#include <math.h>

typedef __attribute__((ext_vector_type(8))) short bf16x8;
typedef __attribute__((ext_vector_type(4))) float f32x4;

#define DEVI __device__ __forceinline__

DEVI float b2f(unsigned int u){ union{unsigned int i; float f;} c; c.i = u<<16; return c.f; }
DEVI unsigned short f2b(float f){
  union{float f; unsigned int i;} c; c.f = f;
  unsigned int r = c.i + 0x7fffu + ((c.i>>16)&1u);
  return (unsigned short)(r>>16);
}
DEVI unsigned int pack2(float a, float b){
  return (unsigned int)f2b(a) | ((unsigned int)f2b(b)<<16);
}
DEVI void unpack8(uint4 u, float* f){
  f[0]=b2f(u.x&0xffffu); f[1]=b2f(u.x>>16);
  f[2]=b2f(u.y&0xffffu); f[3]=b2f(u.y>>16);
  f[4]=b2f(u.z&0xffffu); f[5]=b2f(u.z>>16);
  f[6]=b2f(u.w&0xffffu); f[7]=b2f(u.w>>16);
}
DEVI f32x4 mfma16(bf16x8 a, bf16x8 b, f32x4 c){
  return __builtin_amdgcn_mfma_f32_16x16x32_bf16(a, b, c, 0, 0, 0);
}
DEVI float gelu_fast(float u){
  const float y = 0.7978845608028654f*(u + 0.044715f*u*u*u);
  const float t = __expf(2.f*y);
  const float th = 1.f - 2.f/(t + 1.f);
  return 0.5f*u*(1.f + th);
}
// XOR swizzles
DEVI int swzA(int row, int byi){ return row*256 + (byi ^ ((row&7)<<4)); }      // 64x128 bf16
DEVI int swzQ(int row, int byi){ return row*64  + (byi ^ (((row>>1)&3)<<4)); } // 64x32  bf16
DEVI int swzP(int row, int byi){ return row*128 + (byi ^ ((row&7)<<4)); }      // 64x64 / 32x64
DEVI int swzH(int row, int byi){ return row*512 + (byi ^ ((row&7)<<4)); }      // 64x256 bf16
// fp32 64x128 restage swizzle (write scalar f32, read b128)
DEVI int swzO(int row, int byc){ return row*512 + (byc ^ ((row&7)<<4) ^ (((byc>>7)&3)<<5)); }

// ---------------- K0: weights -> bf16 MFMA-fragment order [frag][lane*8] ----------------
// frag for (group g over N/16, kk over K/32): lane l holds W^T[g*16+(l&15)][kk*32+(l>>4)*8 + 0..7]
__global__ void k_prep(const float* __restrict__ qkvw, const float* __restrict__ projw,
                       const float* __restrict__ w1,   const float* __restrict__ w2,
                       ushort* __restrict__ qkvF, ushort* __restrict__ projF,
                       ushort* __restrict__ w1F,  ushort* __restrict__ w2F)
{
  const int t = blockIdx.x*256 + threadIdx.x;   // 0..8191
  const int l = t & 63, l15 = l & 15, l8 = (l>>4)*8;
  { // w1: K=128 N=512 (w1[k][n], n-major frag): f = g*4+kk, g in [0,32)
    const int f = t>>6, kk = f&3;
    const int col = ((f>>2)<<4) + l15;
    const int k0  = kk*32 + l8;
    ushort* d = w1F + (size_t)f*512 + l*8;
    #pragma unroll
    for(int e=0;e<8;e++) d[e] = f2b(w1[(size_t)(k0+e)*512 + col]);
  }
  { // w2: K=512 N=128: f = g*16+kk16, g in [0,8)
    const int f = t>>6, kk = f&15;
    const int col = ((f>>4)<<4) + l15;
    const int k0  = kk*32 + l8;
    ushort* d = w2F + (size_t)f*512 + l*8;
    #pragma unroll
    for(int e=0;e<8;e++) d[e] = f2b(w2[(size_t)(k0+e)*128 + col]);
  }
  if (t < 6144){ // qkv: K=128 N=384: f = g*4+kk, g in [0,24)
    const int f = t>>6, kk = f&3;
    const int m  = ((f>>2)<<4) + l15;
    const int k0 = kk*32 + l8;
    ushort* d = qkvF + (size_t)f*512 + l*8;
    #pragma unroll
    for(int e=0;e<8;e++) d[e] = f2b(qkvw[(size_t)(k0+e)*384 + m]);
  }
  if (t < 2048){ // proj: K=128 N=128: f = g*4+kk, g in [0,8)
    const int f = t>>6, kk = f&3;
    const int c  = ((f>>2)<<4) + l15;
    const int k0 = kk*32 + l8;
    ushort* d = projF + (size_t)f*512 + l*8;
    #pragma unroll
    for(int e=0;e<8;e++) d[e] = f2b(projw[(size_t)(k0+e)*128 + c]);
  }
}

// ---------------- K1: fused window attention ----------------
__global__ __launch_bounds__(256,2) void k_attn(
    const float*  __restrict__ x,
    const float*  __restrict__ g1, const float* __restrict__ be1,
    const ushort* __restrict__ qkvF, const float* __restrict__ qkvb,
    const ushort* __restrict__ projF, const float* __restrict__ projb,
    const float*  __restrict__ rpbt,
    ushort* __restrict__ x2w)
{
  __shared__ __align__(16) char smem[65536];
  const int tid  = threadIdx.x;
  const int wave = tid>>6, lane = tid&63;
  const int l15 = lane&15, l4 = lane>>4;
  const int wid = blockIdx.x;
  const int b   = wid>>6, wim = wid&63;
  const int wh  = wim>>3, wv = wim&7;

  char* const smA  = smem;                       // 16 KB
  char* const smHd = smem + 16384 + wave*12288;  // per-head 12 KB
  char* const smQ  = smHd;
  char* const smK  = smHd + 4096;
  char* const smVT = smHd + 8192;
  char* const smP  = smHd;                       // overlays Q+K after scores

  const f32x4 Z = {0.f,0.f,0.f,0.f};

  // ---- Phase 1: gather (roll -4,-4) + LayerNorm1 -> smA ----
  {
    const int t  = tid>>2;
    const int cg = (tid&3)*32;
    const int ti = t>>3, tj = t&7;
    const int ho = (wh*8+ti+4)&63, wo = (wv*8+tj+4)&63;
    const float* src = x + ((size_t)(b*4096 + ho*64 + wo))*128 + cg;
    float v[32];
    #pragma unroll
    for(int q=0;q<8;q++){
      const float4 f4 = *(const float4*)(src + q*4);
      v[q*4+0]=f4.x; v[q*4+1]=f4.y; v[q*4+2]=f4.z; v[q*4+3]=f4.w;
    }
    float s=0.f, ss=0.f;
    #pragma unroll
    for(int e=0;e<32;e++){ s+=v[e]; ss+=v[e]*v[e]; }
    s += __shfl_xor(s,1); ss += __shfl_xor(ss,1);
    s += __shfl_xor(s,2); ss += __shfl_xor(ss,2);
    const float mean = s*(1.f/128.f);
    const float varv = fmaxf(ss*(1.f/128.f) - mean*mean, 0.f);
    const float rstd = rsqrtf(varv + 1e-5f);
    #pragma unroll
    for(int q=0;q<4;q++){
      const float4 ga = *(const float4*)(g1 +cg+q*8);
      const float4 gb = *(const float4*)(g1 +cg+q*8+4);
      const float4 ba = *(const float4*)(be1+cg+q*8);
      const float4 bb = *(const float4*)(be1+cg+q*8+4);
      const float* vp = v + q*8;
      uint4 pk;
      pk.x = pack2((vp[0]-mean)*rstd*ga.x+ba.x, (vp[1]-mean)*rstd*ga.y+ba.y);
      pk.y = pack2((vp[2]-mean)*rstd*ga.z+ba.z, (vp[3]-mean)*rstd*ga.w+ba.w);
      pk.z = pack2((vp[4]-mean)*rstd*gb.x+bb.x, (vp[5]-mean)*rstd*gb.y+bb.y);
      pk.w = pack2((vp[6]-mean)*rstd*gb.z+bb.z, (vp[7]-mean)*rstd*gb.w+bb.w);
      *(uint4*)(smA + swzA(t, cg*2 + q*16)) = pk;
    }
  }
  __syncthreads();

  // ---- Phase 2: QKV (coalesced fragment weight loads) ----
  const int headc = wave*32;
  {
    #pragma unroll
    for(int s3=0;s3<3;s3++){
      f32x4 acc[4][2];
      #pragma unroll
      for(int rt=0;rt<4;rt++){ acc[rt][0]=Z; acc[rt][1]=Z; }
      bf16x8 bfr[2][4];
      #pragma unroll
      for(int ct=0;ct<2;ct++)
        #pragma unroll
        for(int kk=0;kk<4;kk++)
          bfr[ct][kk] = *(const bf16x8*)(qkvF + (size_t)((s3*8 + wave*2 + ct)*4 + kk)*512 + lane*8);
      #pragma unroll
      for(int kk=0;kk<4;kk++){
        bf16x8 afr[4];
        #pragma unroll
        for(int rt=0;rt<4;rt++)
          afr[rt] = *(const bf16x8*)(smA + swzA(rt*16+l15, kk*64 + l4*16));
        #pragma unroll
        for(int rt=0;rt<4;rt++)
          #pragma unroll
          for(int ct=0;ct<2;ct++)
            acc[rt][ct] = mfma16(afr[rt], bfr[ct][kk], acc[rt][ct]);
      }
      #pragma unroll
      for(int ct=0;ct<2;ct++){
        const int hd = ct*16 + l15;
        const float bias = qkvb[s3*128 + headc + hd];
        #pragma unroll
        for(int rt=0;rt<4;rt++){
          const int t0 = rt*16 + l4*4;
          if (s3==2){
            uint2 pk;
            pk.x = pack2(acc[rt][ct][0]+bias, acc[rt][ct][1]+bias);
            pk.y = pack2(acc[rt][ct][2]+bias, acc[rt][ct][3]+bias);
            *(uint2*)(smVT + swzP(hd, t0*2)) = pk;
          } else {
            char* const dst = (s3==0) ? smQ : smK;
            const float sc = (s3==0) ? 0.17677669529663687f : 1.f;
            #pragma unroll
            for(int j=0;j<4;j++)
              *(ushort*)(dst + swzQ(t0+j, hd*2)) = f2b((acc[rt][ct][j]+bias)*sc);
          }
        }
      }
    }
  }
  __syncthreads();

  // ---- Phase 3: scores + rpb + mask + softmax -> P ----
  {
    f32x4 S[4][4];
    bf16x8 qfr[4], kfr[4];
    #pragma unroll
    for(int i=0;i<4;i++) qfr[i] = *(const bf16x8*)(smQ + swzQ(i*16+l15, l4*16));
    #pragma unroll
    for(int i=0;i<4;i++) kfr[i] = *(const bf16x8*)(smK + swzQ(i*16+l15, l4*16));
    #pragma unroll
    for(int rt=0;rt<4;rt++)
      #pragma unroll
      for(int ct=0;ct<4;ct++)
        S[rt][ct] = mfma16(qfr[rt], kfr[ct], Z);

    const bool edge = (wh==7) || (wv==7);
    #pragma unroll
    for(int ct=0;ct<4;ct++){
      const int m = ct*16 + l15;
      const int im = m>>3, jm = m&7;
      const int regm = ((wh<7)?0:((im<4)?1:2))*3 + ((wv<7)?0:((jm<4)?1:2));
      #pragma unroll
      for(int rt=0;rt<4;rt++)
        #pragma unroll
        for(int j=0;j<4;j++){
          const int n = rt*16 + l4*4 + j;
          const int in_ = n>>3, jn = n&7;
          float add = rpbt[((in_-im+7)*15 + (jn-jm+7))*4 + wave];
          if (edge){
            const int regn = ((wh<7)?0:((in_<4)?1:2))*3 + ((wv<7)?0:((jn<4)?1:2));
            if (regn != regm) add -= 100.f;
          }
          S[rt][ct][j] += add;
        }
    }
    #pragma unroll
    for(int rt=0;rt<4;rt++)
      #pragma unroll
      for(int j=0;j<4;j++){
        float mx = fmaxf(fmaxf(S[rt][0][j],S[rt][1][j]), fmaxf(S[rt][2][j],S[rt][3][j]));
        mx = fmaxf(mx, __shfl_xor(mx,1));
        mx = fmaxf(mx, __shfl_xor(mx,2));
        mx = fmaxf(mx, __shfl_xor(mx,4));
        mx = fmaxf(mx, __shfl_xor(mx,8));
        float sm = 0.f;
        #pragma unroll
        for(int ct=0;ct<4;ct++){ const float e = __expf(S[rt][ct][j]-mx); S[rt][ct][j]=e; sm+=e; }
        sm += __shfl_xor(sm,1);
        sm += __shfl_xor(sm,2);
        sm += __shfl_xor(sm,4);
        sm += __shfl_xor(sm,8);
        const float inv = 1.f/sm;
        #pragma unroll
        for(int ct=0;ct<4;ct++) S[rt][ct][j] *= inv;
      }
    #pragma unroll
    for(int rt=0;rt<4;rt++)
      #pragma unroll
      for(int j=0;j<4;j++){
        const int n = rt*16 + l4*4 + j;
        #pragma unroll
        for(int ct=0;ct<4;ct++)
          *(ushort*)(smP + swzP(n, (ct*16+l15)*2)) = f2b(S[rt][ct][j]);
      }
  }

  // ---- Phase 4: O = P V -> smA ----
  {
    f32x4 O[4][2];
    #pragma unroll
    for(int rt=0;rt<4;rt++){ O[rt][0]=Z; O[rt][1]=Z; }
    #pragma unroll
    for(int kk=0;kk<2;kk++){
      bf16x8 pfr[4], vfr[2];
      #pragma unroll
      for(int rt=0;rt<4;rt++)
        pfr[rt] = *(const bf16x8*)(smP + swzP(rt*16+l15, kk*64 + l4*16));
      #pragma unroll
      for(int ct=0;ct<2;ct++)
        vfr[ct] = *(const bf16x8*)(smVT + swzP(ct*16+l15, kk*64 + l4*16));
      #pragma unroll
      for(int rt=0;rt<4;rt++)
        #pragma unroll
        for(int ct=0;ct<2;ct++)
          O[rt][ct] = mfma16(pfr[rt], vfr[ct], O[rt][ct]);
    }
    #pragma unroll
    for(int rt=0;rt<4;rt++)
      #pragma unroll
      for(int ct=0;ct<2;ct++)
        #pragma unroll
        for(int j=0;j<4;j++){
          const int t = rt*16 + l4*4 + j;
          *(ushort*)(smA + swzA(t, (headc + ct*16 + l15)*2)) = f2b(O[rt][ct][j]);
        }
  }
  __syncthreads();

  // ---- Phase 5: proj + bias + shortcut -> x2 (window-order) ----
  {
    f32x4 PR[4][2];
    #pragma unroll
    for(int rt=0;rt<4;rt++){ PR[rt][0]=Z; PR[rt][1]=Z; }
    bf16x8 pb[2][4];
    #pragma unroll
    for(int ct=0;ct<2;ct++)
      #pragma unroll
      for(int kk=0;kk<4;kk++)
        pb[ct][kk] = *(const bf16x8*)(projF + (size_t)((wave*2+ct)*4 + kk)*512 + lane*8);
    #pragma unroll
    for(int kk=0;kk<4;kk++){
      bf16x8 afr[4];
      #pragma unroll
      for(int rt=0;rt<4;rt++)
        afr[rt] = *(const bf16x8*)(smA + swzA(rt*16+l15, kk*64 + l4*16));
      #pragma unroll
      for(int rt=0;rt<4;rt++)
        #pragma unroll
        for(int ct=0;ct<2;ct++)
          PR[rt][ct] = mfma16(afr[rt], pb[ct][kk], PR[rt][ct]);
    }
    #pragma unroll
    for(int ct=0;ct<2;ct++){
      const int col = headc + ct*16 + l15;
      const float bias = projb[col];
      #pragma unroll
      for(int rt=0;rt<4;rt++)
        #pragma unroll
        for(int j=0;j<4;j++){
          const int t = rt*16 + l4*4 + j;
          const int ti = t>>3, tj = t&7;
          const int ho = (wh*8+ti+4)&63, wo = (wv*8+tj+4)&63;
          const float sc = x[((size_t)(b*4096 + ho*64 + wo))*128 + col];
          x2w[((size_t)(wid*64 + t))*128 + col] = f2b(PR[rt][ct][j] + bias + sc);
        }
    }
  }
}

// ---------------- K2: fused MLP ----------------
__global__ __launch_bounds__(256,3) void k_mlp(
    const ushort* __restrict__ x2w,
    const float* __restrict__ g2, const float* __restrict__ be2,
    const ushort* __restrict__ w1F, const float* __restrict__ bb1,
    const ushort* __restrict__ w2F, const float* __restrict__ bb2,
    float* __restrict__ outp)
{
  __shared__ __align__(16) char smem[49152];
  char* const smA  = smem;          // 16 KB LN2 tile
  char* const smHd = smem + 16384;  // 32 KB hidden half / fp32 OA restage
  const int tid  = threadIdx.x;
  const int wave = tid>>6, lane = tid&63;
  const int l15 = lane&15, l4 = lane>>4;
  const int wid = blockIdx.x;
  const int b   = wid>>6, wim = wid&63;
  const int wh  = wim>>3, wv = wim&7;
  const f32x4 Z = {0.f,0.f,0.f,0.f};

  const int t_row = tid>>2;
  const int cg    = (tid&3)*32;
  const int ti_r = t_row>>3, tj_r = t_row&7;
  const int ho_r = (wh*8+ti_r+4)&63, wo_r = (wv*8+tj_r+4)&63;

  float x2v[32];  // x2 row-chunk, kept live for the residual

  // LN2 on x2 rows (single global read)
  {
    const ushort* src = x2w + ((size_t)(wid*64 + t_row))*128 + cg;
    unpack8(*(const uint4*)(src   ), x2v   );
    unpack8(*(const uint4*)(src+ 8), x2v+ 8);
    unpack8(*(const uint4*)(src+16), x2v+16);
    unpack8(*(const uint4*)(src+24), x2v+24);
    float s=0.f, ss=0.f;
    #pragma unroll
    for(int e=0;e<32;e++){ s+=x2v[e]; ss+=x2v[e]*x2v[e]; }
    s += __shfl_xor(s,1); ss += __shfl_xor(ss,1);
    s += __shfl_xor(s,2); ss += __shfl_xor(ss,2);
    const float mean = s*(1.f/128.f);
    const float varv = fmaxf(ss*(1.f/128.f) - mean*mean, 0.f);
    const float rstd = rsqrtf(varv + 1e-5f);
    #pragma unroll
    for(int q=0;q<4;q++){
      const float4 ga = *(const float4*)(g2 +cg+q*8);
      const float4 gb = *(const float4*)(g2 +cg+q*8+4);
      const float4 ba = *(const float4*)(be2+cg+q*8);
      const float4 bb = *(const float4*)(be2+cg+q*8+4);
      const float* vp = x2v + q*8;
      uint4 pk;
      pk.x = pack2((vp[0]-mean)*rstd*ga.x+ba.x, (vp[1]-mean)*rstd*ga.y+ba.y);
      pk.y = pack2((vp[2]-mean)*rstd*ga.z+ba.z, (vp[3]-mean)*rstd*ga.w+ba.w);
      pk.z = pack2((vp[4]-mean)*rstd*gb.x+bb.x, (vp[5]-mean)*rstd*gb.y+bb.y);
      pk.w = pack2((vp[6]-mean)*rstd*gb.z+bb.z, (vp[7]-mean)*rstd*gb.w+bb.w);
      *(uint4*)(smA + swzA(t_row, cg*2 + q*16)) = pk;
    }
  }
  __syncthreads();

  f32x4 OA[4][2];
  #pragma unroll
  for(int rt=0;rt<4;rt++){ OA[rt][0]=Z; OA[rt][1]=Z; }

  #pragma unroll
  for(int ph=0; ph<2; ++ph){
    f32x4 HA[4][4];
    #pragma unroll
    for(int rt=0;rt<4;rt++)
      #pragma unroll
      for(int ct=0;ct<4;ct++) HA[rt][ct]=Z;
    #pragma unroll
    for(int kk=0;kk<4;kk++){
      bf16x8 afr[4];
      #pragma unroll
      for(int rt=0;rt<4;rt++)
        afr[rt] = *(const bf16x8*)(smA + swzA(rt*16+l15, kk*64 + l4*16));
      bf16x8 bfr[4];
      #pragma unroll
      for(int ct=0;ct<4;ct++)
        bfr[ct] = *(const bf16x8*)(w1F + (size_t)((ph*16 + wave*4 + ct)*4 + kk)*512 + lane*8);
      #pragma unroll
      for(int rt=0;rt<4;rt++)
        #pragma unroll
        for(int ct=0;ct<4;ct++)
          HA[rt][ct] = mfma16(afr[rt], bfr[ct], HA[rt][ct]);
    }
    if (ph==1) __syncthreads();   // WAR: all waves done reading smHd half 0
    #pragma unroll
    for(int ct=0;ct<4;ct++){
      const int ch = wave*64 + ct*16 + l15;
      const float bias = bb1[ph*256 + ch];
      #pragma unroll
      for(int rt=0;rt<4;rt++)
        #pragma unroll
        for(int j=0;j<4;j++){
          const float u = HA[rt][ct][j] + bias;
          *(ushort*)(smHd + swzH(rt*16+l4*4+j, ch*2)) = f2b(gelu_fast(u));
        }
    }
    __syncthreads();
    #pragma unroll
    for(int kk=0;kk<8;kk++){
      bf16x8 afr[4];
      #pragma unroll
      for(int rt=0;rt<4;rt++)
        afr[rt] = *(const bf16x8*)(smHd + swzH(rt*16+l15, kk*64 + l4*16));
      bf16x8 bfr[2];
      #pragma unroll
      for(int ct=0;ct<2;ct++)
        bfr[ct] = *(const bf16x8*)(w2F + (size_t)((wave*2+ct)*16 + ph*8 + kk)*512 + lane*8);
      #pragma unroll
      for(int rt=0;rt<4;rt++)
        #pragma unroll
        for(int ct=0;ct<2;ct++)
          OA[rt][ct] = mfma16(afr[rt], bfr[ct], OA[rt][ct]);
    }
  }
  __syncthreads();   // all waves done reading smHd (hidden half 1)

  // stage OA fp32 into smHd (64 rows x 128 f32, swizzled)
  #pragma unroll
  for(int ct=0;ct<2;ct++){
    const int col = wave*32 + ct*16 + l15;
    #pragma unroll
    for(int rt=0;rt<4;rt++)
      #pragma unroll
      for(int j=0;j<4;j++){
        const int t = rt*16 + l4*4 + j;
        *(float*)(smHd + swzO(t, col*4)) = OA[rt][ct][j];
      }
  }
  __syncthreads();

  // out = x2(regs) + bias2 + mlp_out, coalesced fp32 row stores (shift-back scatter by row)
  {
    float* dst = outp + ((size_t)(b*4096 + ho_r*64 + wo_r))*128 + cg;
    #pragma unroll
    for(int q=0;q<8;q++){
      const f32x4 o4 = *(const f32x4*)(smHd + swzO(t_row, (cg+q*4)*4));
      const float4 b4 = *(const float4*)(bb2 + cg + q*4);
      float4 r;
      r.x = o4[0] + b4.x + x2v[q*4+0];
      r.y = o4[1] + b4.y + x2v[q*4+1];
      r.z = o4[2] + b4.z + x2v[q*4+2];
      r.w = o4[3] + b4.w + x2v[q*4+3];
      *(float4*)(dst + q*4) = r;
    }
  }
}

extern "C" void kernel_launch(void* const* d_in, const int* in_sizes, int n_in,
                              void* d_out, int out_size, void* d_ws, size_t ws_size,
                              hipStream_t stream) {
  (void)in_sizes; (void)n_in; (void)out_size; (void)ws_size;
  const float* x     = (const float*)d_in[0];
  const float* n1g   = (const float*)d_in[1];
  const float* n1b   = (const float*)d_in[2];
  const float* qkvw  = (const float*)d_in[3];
  const float* qkvb  = (const float*)d_in[4];
  const float* projw = (const float*)d_in[5];
  const float* projb = (const float*)d_in[6];
  const float* rpbt  = (const float*)d_in[7];
  const float* n2g   = (const float*)d_in[8];
  const float* n2b   = (const float*)d_in[9];
  const float* w1    = (const float*)d_in[10];
  const float* b1    = (const float*)d_in[11];
  const float* w2    = (const float*)d_in[12];
  const float* b2    = (const float*)d_in[13];
  float* outp = (float*)d_out;

  ushort* ws    = (ushort*)d_ws;
  ushort* x2w   = ws;                  // 16,777,216 bf16
  ushort* qkvF  = ws + 16777216;       // 49152
  ushort* projF = qkvF + 49152;        // 16384
  ushort* w1F   = projF + 16384;       // 65536
  ushort* w2F   = w1F + 65536;         // 65536

  k_prep<<<32, 256, 0, stream>>>(qkvw, projw, w1, w2, qkvF, projF, w1F, w2F);
  k_attn<<<2048, 256, 0, stream>>>(x, n1g, n1b, qkvF, qkvb, projF, projb, rpbt, x2w);
  k_mlp <<<2048, 256, 0, stream>>>(x2w, n2g, n2b, w1F, b1, w2F, b2, outp);
}

// Round 6
// 209.990 us; speedup vs baseline: 1.3101x; 1.2812x over previous
//
// Swin block fwd, MI355X gfx950. Round 6: k_mlp rebuilt as M=256/block (4 windows), weights
// LDS-staged once per block (double-buffered 64-hid chunks), hidden kept in REGISTERS:
// GEMM1 D-frag feeds v_mfma_f32_16x16x16_bf16 GEMM2 directly (layout match, no repack).
#include <hip/hip_runtime.h>
#include <math.h>

typedef __attribute__((ext_vector_type(8))) short bf16x8;
typedef __attribute__((ext_vector_type(4))) short bf16x4;
typedef __attribute__((ext_vector_type(4))) float f32x4;
typedef __attribute__((ext_vector_type(4))) unsigned short u16x4;

#define DEVI __device__ __forceinline__

DEVI float b2f(unsigned int u){ union{unsigned int i; float f;} c; c.i = u<<16; return c.f; }
DEVI unsigned short f2b(float f){
  union{float f; unsigned int i;} c; c.f = f;
  unsigned int r = c.i + 0x7fffu + ((c.i>>16)&1u);
  return (unsigned short)(r>>16);
}
DEVI unsigned int pack2(float a, float b){
  return (unsigned int)f2b(a) | ((unsigned int)f2b(b)<<16);
}
DEVI void unpack8(uint4 u, float* f){
  f[0]=b2f(u.x&0xffffu); f[1]=b2f(u.x>>16);
  f[2]=b2f(u.y&0xffffu); f[3]=b2f(u.y>>16);
  f[4]=b2f(u.z&0xffffu); f[5]=b2f(u.z>>16);
  f[6]=b2f(u.w&0xffffu); f[7]=b2f(u.w>>16);
}
DEVI f32x4 mfma16(bf16x8 a, bf16x8 b, f32x4 c){
  return __builtin_amdgcn_mfma_f32_16x16x32_bf16(a, b, c, 0, 0, 0);
}
DEVI f32x4 mfma16x16(bf16x4 a, bf16x4 b, f32x4 c){
#if __has_builtin(__builtin_amdgcn_mfma_f32_16x16x16bf16_1k)
  return __builtin_amdgcn_mfma_f32_16x16x16bf16_1k(a, b, c, 0, 0, 0);
#else
  f32x4 d = c;
  asm volatile("v_mfma_f32_16x16x16_bf16 %0, %1, %2, %0" : "+v"(d) : "v"(a), "v"(b));
  return d;
#endif
}
DEVI float gelu_fast(float u){
  const float y = 0.7978845608028654f*(u + 0.044715f*u*u*u);
  const float t = __expf(2.f*y);
  const float th = 1.f - 2.f/(t + 1.f);
  return 0.5f*u*(1.f + th);
}
// XOR swizzles
DEVI int swzA(int row, int byi){ return row*256 + (byi ^ ((row&7)<<4)); }      // rows x 128 bf16
DEVI int swzQ(int row, int byi){ return row*64  + (byi ^ (((row>>1)&3)<<4)); } // 64x32  bf16
DEVI int swzP(int row, int byi){ return row*128 + (byi ^ ((row&7)<<4)); }      // 64x64 / 32x64

// ---------------- K0: weights -> bf16 MFMA-fragment order ----------------
// qkvF/projF: 16x16x32 B-frags (8 bf16/lane).  w1F: 16x16x32 A-frags [chunk8][hidg4][kk4].
// w2F: 16x16x16 A-frags [chunk8][ocg8][h16g4] (4 bf16/lane).
__global__ void k_prep(const float* __restrict__ qkvw, const float* __restrict__ projw,
                       const float* __restrict__ w1,   const float* __restrict__ w2,
                       ushort* __restrict__ qkvF, ushort* __restrict__ projF,
                       ushort* __restrict__ w1F,  ushort* __restrict__ w2F)
{
  const int t = blockIdx.x*256 + threadIdx.x;   // 0..16383
  const int l = t&63, fr = t>>6;                // frag id 0..255
  const int l15 = l&15, l4 = l>>4;
  { // w2F: 256 frags x 512B ; lane: w2[hid0+e][oc], e=0..3
    const int c = fr>>5, og = (fr>>2)&7, h = fr&3;
    const int oc = og*16 + l15, hid0 = c*64 + h*16 + l4*4;
    ushort* d = w2F + (size_t)fr*256 + l*4;
    #pragma unroll
    for(int e=0;e<4;e++) d[e] = f2b(w2[(size_t)(hid0+e)*128 + oc]);
  }
  if (fr < 128){ // w1F: 128 frags x 1KB ; lane: w1[k0+e][hid], e=0..7
    const int c = fr>>4, hg = (fr>>2)&3, kk = fr&3;
    const int hid = c*64 + hg*16 + l15, k0 = kk*32 + l4*8;
    ushort* d = w1F + (size_t)fr*512 + l*8;
    #pragma unroll
    for(int e=0;e<8;e++) d[e] = f2b(w1[(size_t)(k0+e)*512 + hid]);
  }
  if (fr < 96){ // qkvF: fr = (s3*8+g)*4+kk
    const int s3 = fr>>5, g = (fr>>2)&7, kk = fr&3;
    const int col = s3*128 + g*16 + l15, k0 = kk*32 + l4*8;
    ushort* d = qkvF + (size_t)fr*512 + l*8;
    #pragma unroll
    for(int e=0;e<8;e++) d[e] = f2b(qkvw[(size_t)(k0+e)*384 + col]);
  }
  if (fr < 32){ // projF
    const int g = fr>>2, kk = fr&3;
    const int col = g*16 + l15, k0 = kk*32 + l4*8;
    ushort* d = projF + (size_t)fr*512 + l*8;
    #pragma unroll
    for(int e=0;e<8;e++) d[e] = f2b(projw[(size_t)(k0+e)*128 + col]);
  }
}

// ---------------- K1: fused window attention (unchanged from R5) ----------------
__global__ __launch_bounds__(256,2) void k_attn(
    const float*  __restrict__ x,
    const float*  __restrict__ g1, const float* __restrict__ be1,
    const ushort* __restrict__ qkvF, const float* __restrict__ qkvb,
    const ushort* __restrict__ projF, const float* __restrict__ projb,
    const float*  __restrict__ rpbt,
    ushort* __restrict__ x2w)
{
  __shared__ __align__(16) char smem[65536];
  const int tid  = threadIdx.x;
  const int wave = tid>>6, lane = tid&63;
  const int l15 = lane&15, l4 = lane>>4;
  const int wid = blockIdx.x;
  const int b   = wid>>6, wim = wid&63;
  const int wh  = wim>>3, wv = wim&7;

  char* const smA  = smem;
  char* const smHd = smem + 16384 + wave*12288;
  char* const smQ  = smHd;
  char* const smK  = smHd + 4096;
  char* const smVT = smHd + 8192;
  char* const smP  = smHd;

  const f32x4 Z = {0.f,0.f,0.f,0.f};

  { // Phase 1: gather (roll -4,-4) + LN1 -> smA
    const int t  = tid>>2;
    const int cg = (tid&3)*32;
    const int ti = t>>3, tj = t&7;
    const int ho = (wh*8+ti+4)&63, wo = (wv*8+tj+4)&63;
    const float* src = x + ((size_t)(b*4096 + ho*64 + wo))*128 + cg;
    float v[32];
    #pragma unroll
    for(int q=0;q<8;q++){
      const float4 f4 = *(const float4*)(src + q*4);
      v[q*4+0]=f4.x; v[q*4+1]=f4.y; v[q*4+2]=f4.z; v[q*4+3]=f4.w;
    }
    float s=0.f, ss=0.f;
    #pragma unroll
    for(int e=0;e<32;e++){ s+=v[e]; ss+=v[e]*v[e]; }
    s += __shfl_xor(s,1); ss += __shfl_xor(ss,1);
    s += __shfl_xor(s,2); ss += __shfl_xor(ss,2);
    const float mean = s*(1.f/128.f);
    const float varv = fmaxf(ss*(1.f/128.f) - mean*mean, 0.f);
    const float rstd = rsqrtf(varv + 1e-5f);
    #pragma unroll
    for(int q=0;q<4;q++){
      const float4 ga = *(const float4*)(g1 +cg+q*8);
      const float4 gb = *(const float4*)(g1 +cg+q*8+4);
      const float4 ba = *(const float4*)(be1+cg+q*8);
      const float4 bb = *(const float4*)(be1+cg+q*8+4);
      const float* vp = v + q*8;
      uint4 pk;
      pk.x = pack2((vp[0]-mean)*rstd*ga.x+ba.x, (vp[1]-mean)*rstd*ga.y+ba.y);
      pk.y = pack2((vp[2]-mean)*rstd*ga.z+ba.z, (vp[3]-mean)*rstd*ga.w+ba.w);
      pk.z = pack2((vp[4]-mean)*rstd*gb.x+bb.x, (vp[5]-mean)*rstd*gb.y+bb.y);
      pk.w = pack2((vp[6]-mean)*rstd*gb.z+bb.z, (vp[7]-mean)*rstd*gb.w+bb.w);
      *(uint4*)(smA + swzA(t, cg*2 + q*16)) = pk;
    }
  }
  __syncthreads();

  const int headc = wave*32;
  { // Phase 2: QKV
    #pragma unroll
    for(int s3=0;s3<3;s3++){
      f32x4 acc[4][2];
      #pragma unroll
      for(int rt=0;rt<4;rt++){ acc[rt][0]=Z; acc[rt][1]=Z; }
      bf16x8 bfr[2][4];
      #pragma unroll
      for(int ct=0;ct<2;ct++)
        #pragma unroll
        for(int kk=0;kk<4;kk++)
          bfr[ct][kk] = *(const bf16x8*)(qkvF + (size_t)((s3*8 + wave*2 + ct)*4 + kk)*512 + lane*8);
      #pragma unroll
      for(int kk=0;kk<4;kk++){
        bf16x8 afr[4];
        #pragma unroll
        for(int rt=0;rt<4;rt++)
          afr[rt] = *(const bf16x8*)(smA + swzA(rt*16+l15, kk*64 + l4*16));
        #pragma unroll
        for(int rt=0;rt<4;rt++)
          #pragma unroll
          for(int ct=0;ct<2;ct++)
            acc[rt][ct] = mfma16(afr[rt], bfr[ct][kk], acc[rt][ct]);
      }
      #pragma unroll
      for(int ct=0;ct<2;ct++){
        const int hd = ct*16 + l15;
        const float bias = qkvb[s3*128 + headc + hd];
        #pragma unroll
        for(int rt=0;rt<4;rt++){
          const int t0 = rt*16 + l4*4;
          if (s3==2){
            uint2 pk;
            pk.x = pack2(acc[rt][ct][0]+bias, acc[rt][ct][1]+bias);
            pk.y = pack2(acc[rt][ct][2]+bias, acc[rt][ct][3]+bias);
            *(uint2*)(smVT + swzP(hd, t0*2)) = pk;
          } else {
            char* const dst = (s3==0) ? smQ : smK;
            const float sc = (s3==0) ? 0.17677669529663687f : 1.f;
            #pragma unroll
            for(int j=0;j<4;j++)
              *(ushort*)(dst + swzQ(t0+j, hd*2)) = f2b((acc[rt][ct][j]+bias)*sc);
          }
        }
      }
    }
  }
  __syncthreads();

  { // Phase 3: scores + rpb + mask + softmax -> P
    f32x4 S[4][4];
    bf16x8 qfr[4], kfr[4];
    #pragma unroll
    for(int i=0;i<4;i++) qfr[i] = *(const bf16x8*)(smQ + swzQ(i*16+l15, l4*16));
    #pragma unroll
    for(int i=0;i<4;i++) kfr[i] = *(const bf16x8*)(smK + swzQ(i*16+l15, l4*16));
    #pragma unroll
    for(int rt=0;rt<4;rt++)
      #pragma unroll
      for(int ct=0;ct<4;ct++)
        S[rt][ct] = mfma16(qfr[rt], kfr[ct], Z);

    const bool edge = (wh==7) || (wv==7);
    #pragma unroll
    for(int ct=0;ct<4;ct++){
      const int m = ct*16 + l15;
      const int im = m>>3, jm = m&7;
      const int regm = ((wh<7)?0:((im<4)?1:2))*3 + ((wv<7)?0:((jm<4)?1:2));
      #pragma unroll
      for(int rt=0;rt<4;rt++)
        #pragma unroll
        for(int j=0;j<4;j++){
          const int n = rt*16 + l4*4 + j;
          const int in_ = n>>3, jn = n&7;
          float add = rpbt[((in_-im+7)*15 + (jn-jm+7))*4 + wave];
          if (edge){
            const int regn = ((wh<7)?0:((in_<4)?1:2))*3 + ((wv<7)?0:((jn<4)?1:2));
            if (regn != regm) add -= 100.f;
          }
          S[rt][ct][j] += add;
        }
    }
    #pragma unroll
    for(int rt=0;rt<4;rt++)
      #pragma unroll
      for(int j=0;j<4;j++){
        float mx = fmaxf(fmaxf(S[rt][0][j],S[rt][1][j]), fmaxf(S[rt][2][j],S[rt][3][j]));
        mx = fmaxf(mx, __shfl_xor(mx,1));
        mx = fmaxf(mx, __shfl_xor(mx,2));
        mx = fmaxf(mx, __shfl_xor(mx,4));
        mx = fmaxf(mx, __shfl_xor(mx,8));
        float sm = 0.f;
        #pragma unroll
        for(int ct=0;ct<4;ct++){ const float e = __expf(S[rt][ct][j]-mx); S[rt][ct][j]=e; sm+=e; }
        sm += __shfl_xor(sm,1);
        sm += __shfl_xor(sm,2);
        sm += __shfl_xor(sm,4);
        sm += __shfl_xor(sm,8);
        const float inv = 1.f/sm;
        #pragma unroll
        for(int ct=0;ct<4;ct++) S[rt][ct][j] *= inv;
      }
    #pragma unroll
    for(int rt=0;rt<4;rt++)
      #pragma unroll
      for(int j=0;j<4;j++){
        const int n = rt*16 + l4*4 + j;
        #pragma unroll
        for(int ct=0;ct<4;ct++)
          *(ushort*)(smP + swzP(n, (ct*16+l15)*2)) = f2b(S[rt][ct][j]);
      }
  }

  { // Phase 4: O = P V -> smA
    f32x4 O[4][2];
    #pragma unroll
    for(int rt=0;rt<4;rt++){ O[rt][0]=Z; O[rt][1]=Z; }
    #pragma unroll
    for(int kk=0;kk<2;kk++){
      bf16x8 pfr[4], vfr[2];
      #pragma unroll
      for(int rt=0;rt<4;rt++)
        pfr[rt] = *(const bf16x8*)(smP + swzP(rt*16+l15, kk*64 + l4*16));
      #pragma unroll
      for(int ct=0;ct<2;ct++)
        vfr[ct] = *(const bf16x8*)(smVT + swzP(ct*16+l15, kk*64 + l4*16));
      #pragma unroll
      for(int rt=0;rt<4;rt++)
        #pragma unroll
        for(int ct=0;ct<2;ct++)
          O[rt][ct] = mfma16(pfr[rt], vfr[ct], O[rt][ct]);
    }
    #pragma unroll
    for(int rt=0;rt<4;rt++)
      #pragma unroll
      for(int ct=0;ct<2;ct++)
        #pragma unroll
        for(int j=0;j<4;j++){
          const int t = rt*16 + l4*4 + j;
          *(ushort*)(smA + swzA(t, (headc + ct*16 + l15)*2)) = f2b(O[rt][ct][j]);
        }
  }
  __syncthreads();

  { // Phase 5: proj + bias + shortcut -> x2 (window-order)
    f32x4 PR[4][2];
    #pragma unroll
    for(int rt=0;rt<4;rt++){ PR[rt][0]=Z; PR[rt][1]=Z; }
    bf16x8 pb[2][4];
    #pragma unroll
    for(int ct=0;ct<2;ct++)
      #pragma unroll
      for(int kk=0;kk<4;kk++)
        pb[ct][kk] = *(const bf16x8*)(projF + (size_t)((wave*2+ct)*4 + kk)*512 + lane*8);
    #pragma unroll
    for(int kk=0;kk<4;kk++){
      bf16x8 afr[4];
      #pragma unroll
      for(int rt=0;rt<4;rt++)
        afr[rt] = *(const bf16x8*)(smA + swzA(rt*16+l15, kk*64 + l4*16));
      #pragma unroll
      for(int rt=0;rt<4;rt++)
        #pragma unroll
        for(int ct=0;ct<2;ct++)
          PR[rt][ct] = mfma16(afr[rt], pb[ct][kk], PR[rt][ct]);
    }
    #pragma unroll
    for(int ct=0;ct<2;ct++){
      const int col = headc + ct*16 + l15;
      const float bias = projb[col];
      #pragma unroll
      for(int rt=0;rt<4;rt++)
        #pragma unroll
        for(int j=0;j<4;j++){
          const int t = rt*16 + l4*4 + j;
          const int ti = t>>3, tj = t&7;
          const int ho = (wh*8+ti+4)&63, wo = (wv*8+tj+4)&63;
          const float sc = x[((size_t)(b*4096 + ho*64 + wo))*128 + col];
          x2w[((size_t)(wid*64 + t))*128 + col] = f2b(PR[rt][ct][j] + bias + sc);
        }
    }
  }
}

// ---------------- K2: MLP, M=256/block, weights LDS-staged, hidden in registers ----------------
__global__ __launch_bounds__(512,1) void k_mlp2(
    const ushort* __restrict__ x2w,
    const float* __restrict__ g2, const float* __restrict__ be2,
    const ushort* __restrict__ w1F, const float* __restrict__ bb1,
    const ushort* __restrict__ w2F, const float* __restrict__ bb2,
    float* __restrict__ outp)
{
  extern __shared__ __align__(16) char smem[];
  char* const smX  = smem;            // 64 KB: 256 tokens x 128 ch bf16 (swzA)
  char* const smW0 = smem + 65536;    // 32 KB: [w1 chunk 16KB][w2 chunk 16KB]
  char* const smW1 = smem + 98304;    // 32 KB
  const int tid  = threadIdx.x;
  const int wave = tid>>6, lane = tid&63;
  const int l15 = lane&15, l4 = lane>>4;
  const int gblk = blockIdx.x;        // 0..511 (4 windows each)
  const f32x4 Z = {0.f,0.f,0.f,0.f};

  // weight staging: thread t<256 -> w1 chunk bytes [t*64,+64); t>=256 -> w2 chunk
  const ushort* const wsrc = (tid & 256) ? w2F : w1F;
  const int soff = (tid & 255) * 32;            // ushorts
  const int loff = ((tid & 256) ? 16384 : 0) + (tid & 255)*64;
  uint4 stg0, stg1, stg2, stg3;
  {
    const uint4* p = (const uint4*)(wsrc + soff);   // chunk 0
    stg0 = p[0]; stg1 = p[1]; stg2 = p[2]; stg3 = p[3];
  }

  // ---- LN2: 2 passes of 128 tokens -> smX ----
  {
    const int sub = tid>>2;
    const int cg  = (tid&3)*32;
    #pragma unroll
    for(int p=0;p<2;++p){
      const int tk = p*128 + sub;
      const ushort* src = x2w + ((size_t)(gblk*256 + tk))*128 + cg;
      float v[32];
      unpack8(*(const uint4*)(src   ), v   );
      unpack8(*(const uint4*)(src+ 8), v+ 8);
      unpack8(*(const uint4*)(src+16), v+16);
      unpack8(*(const uint4*)(src+24), v+24);
      float s=0.f, ss=0.f;
      #pragma unroll
      for(int e=0;e<32;e++){ s+=v[e]; ss+=v[e]*v[e]; }
      s += __shfl_xor(s,1); ss += __shfl_xor(ss,1);
      s += __shfl_xor(s,2); ss += __shfl_xor(ss,2);
      const float mean = s*(1.f/128.f);
      const float varv = fmaxf(ss*(1.f/128.f) - mean*mean, 0.f);
      const float rstd = rsqrtf(varv + 1e-5f);
      #pragma unroll
      for(int q=0;q<4;q++){
        const float4 ga = *(const float4*)(g2 +cg+q*8);
        const float4 gb = *(const float4*)(g2 +cg+q*8+4);
        const float4 ba = *(const float4*)(be2+cg+q*8);
        const float4 bb = *(const float4*)(be2+cg+q*8+4);
        const float* vp = v + q*8;
        uint4 pk;
        pk.x = pack2((vp[0]-mean)*rstd*ga.x+ba.x, (vp[1]-mean)*rstd*ga.y+ba.y);
        pk.y = pack2((vp[2]-mean)*rstd*ga.z+ba.z, (vp[3]-mean)*rstd*ga.w+ba.w);
        pk.z = pack2((vp[4]-mean)*rstd*gb.x+bb.x, (vp[5]-mean)*rstd*gb.y+bb.y);
        pk.w = pack2((vp[6]-mean)*rstd*gb.z+bb.z, (vp[7]-mean)*rstd*gb.w+bb.w);
        *(uint4*)(smX + swzA(tk, cg*2 + q*16)) = pk;
      }
    }
  }
  { // commit chunk 0
    uint4* d = (uint4*)(smW0 + loff);
    d[0]=stg0; d[1]=stg1; d[2]=stg2; d[3]=stg3;
  }
  __syncthreads();

  f32x4 OA[8][2];
  #pragma unroll
  for(int ocg=0;ocg<8;++ocg){ OA[ocg][0]=Z; OA[ocg][1]=Z; }

  for (int c=0; c<8; ++c){
    char* const buf = (c&1) ? smW1 : smW0;
    if (c<7){
      const uint4* p = (const uint4*)(wsrc + (size_t)(c+1)*8192 + soff);
      stg0 = p[0]; stg1 = p[1]; stg2 = p[2]; stg3 = p[3];
    }
    const int hidb = c*64;
    #pragma unroll
    for (int tokg=0; tokg<2; ++tokg){
      const int trow = wave*32 + tokg*16 + l15;
      bf16x8 xf[4];
      #pragma unroll
      for(int kk=0;kk<4;++kk)
        xf[kk] = *(const bf16x8*)(smX + swzA(trow, kk*64 + l4*16));
      // GEMM1: H^T chunk (64 hid x 16 tok), D: lane=token, rows=hid
      f32x4 acc1[4] = {Z,Z,Z,Z};
      #pragma unroll
      for(int hg=0; hg<4; ++hg)
        #pragma unroll
        for(int kk=0; kk<4; ++kk){
          const bf16x8 wf = *(const bf16x8*)(buf + (hg*4+kk)*1024 + lane*16);
          acc1[hg] = mfma16(wf, xf[kk], acc1[hg]);
        }
      // bias + gelu + pack to 16x16x16 B-frags (layout match: hid = l4*4+j)
      bf16x4 Hf[4];
      #pragma unroll
      for(int hg=0; hg<4; ++hg){
        const float4 b4 = *(const float4*)(bb1 + hidb + hg*16 + l4*4);
        bf16x4 hv;
        hv[0] = (short)f2b(gelu_fast(acc1[hg][0]+b4.x));
        hv[1] = (short)f2b(gelu_fast(acc1[hg][1]+b4.y));
        hv[2] = (short)f2b(gelu_fast(acc1[hg][2]+b4.z));
        hv[3] = (short)f2b(gelu_fast(acc1[hg][3]+b4.w));
        Hf[hg] = hv;
      }
      // GEMM2 partial: D: lane=token, rows=oc
      #pragma unroll
      for(int ocg=0; ocg<8; ++ocg)
        #pragma unroll
        for(int hg=0; hg<4; ++hg){
          const bf16x4 w2f = *(const bf16x4*)(buf + 16384 + (ocg*4+hg)*512 + lane*8);
          OA[ocg][tokg] = mfma16x16(w2f, Hf[hg], OA[ocg][tokg]);
        }
    }
    if (c<7){
      char* const nbuf = (c&1) ? smW0 : smW1;
      uint4* d = (uint4*)(nbuf + loff);
      d[0]=stg0; d[1]=stg1; d[2]=stg2; d[3]=stg3;
    }
    __syncthreads();
  }

  // ---- epilogue: restage raw x2 into smX (coalesced), then fused residual stores ----
  {
    const int sub = tid>>2;
    const int cg  = (tid&3)*32;
    #pragma unroll
    for(int p=0;p<2;++p){
      const int tk = p*128 + sub;
      const uint4* src = (const uint4*)(x2w + ((size_t)(gblk*256 + tk))*128 + cg);
      #pragma unroll
      for(int q=0;q<4;q++) *(uint4*)(smX + swzA(tk, cg*2 + q*16)) = src[q];
    }
  }
  __syncthreads();
  #pragma unroll
  for(int tokg=0; tokg<2; ++tokg){
    const int tk  = wave*32 + tokg*16 + l15;
    const int wid = gblk*4 + (tk>>6);
    const int n   = tk & 63;
    const int bb  = wid>>6, wim = wid&63;
    const int wh  = wim>>3, wv = wim&7;
    const int ti  = n>>3,  tj = n&7;
    const int ho  = (wh*8+ti+4)&63, wo = (wv*8+tj+4)&63;
    float* const drow = outp + ((size_t)(bb*4096 + ho*64 + wo))*128;
    #pragma unroll
    for(int ocg=0; ocg<8; ++ocg){
      const int oc = ocg*16 + l4*4;
      const float4 b4 = *(const float4*)(bb2 + oc);
      const u16x4 xr = *(const u16x4*)(smX + swzA(tk, oc*2));
      f32x4 r = OA[ocg][tokg];
      r[0] += b4.x + b2f(xr[0]);
      r[1] += b4.y + b2f(xr[1]);
      r[2] += b4.z + b2f(xr[2]);
      r[3] += b4.w + b2f(xr[3]);
      __builtin_nontemporal_store(r, (f32x4*)(drow + oc));
    }
  }
}

extern "C" void kernel_launch(void* const* d_in, const int* in_sizes, int n_in,
                              void* d_out, int out_size, void* d_ws, size_t ws_size,
                              hipStream_t stream) {
  (void)in_sizes; (void)n_in; (void)out_size; (void)ws_size;
  const float* x     = (const float*)d_in[0];
  const float* n1g   = (const float*)d_in[1];
  const float* n1b   = (const float*)d_in[2];
  const float* qkvw  = (const float*)d_in[3];
  const float* qkvb  = (const float*)d_in[4];
  const float* projw = (const float*)d_in[5];
  const float* projb = (const float*)d_in[6];
  const float* rpbt  = (const float*)d_in[7];
  const float* n2g   = (const float*)d_in[8];
  const float* n2b   = (const float*)d_in[9];
  const float* w1    = (const float*)d_in[10];
  const float* b1    = (const float*)d_in[11];
  const float* w2    = (const float*)d_in[12];
  const float* b2    = (const float*)d_in[13];
  float* outp = (float*)d_out;

  ushort* ws    = (ushort*)d_ws;
  ushort* x2w   = ws;                  // 16,777,216 bf16
  ushort* qkvF  = ws + 16777216;       // 49152
  ushort* projF = qkvF + 49152;        // 16384
  ushort* w1F   = projF + 16384;       // 65536 (8 chunks x 8192)
  ushort* w2F   = w1F + 65536;         // 65536 (8 chunks x 8192)

  k_prep<<<64, 256, 0, stream>>>(qkvw, projw, w1, w2, qkvF, projF, w1F, w2F);
  k_attn<<<2048, 256, 0, stream>>>(x, n1g, n1b, qkvF, qkvb, projF, projb, rpbt, x2w);
  k_mlp2<<<512, 512, 131072, stream>>>(x2w, n2g, n2b, w1F, b1, w2F, b2, outp);
}

// Round 7
// 188.121 us; speedup vs baseline: 1.4623x; 1.1162x over previous
//
// Swin block fwd, MI355X gfx950. Round 7: k_attn rebuilt — S^T scores, P & V in registers
// (16x16x16 layout-match trick), rpb pre-expanded, fp32 LDS epilogue restage, 48KB LDS (3 blk/CU).
// k_mlp2 (R6, validated) unchanged.
#include <hip/hip_runtime.h>
#include <math.h>

typedef __attribute__((ext_vector_type(8))) short bf16x8;
typedef __attribute__((ext_vector_type(4))) short bf16x4;
typedef __attribute__((ext_vector_type(4))) float f32x4;
typedef __attribute__((ext_vector_type(4))) unsigned short u16x4;

#define DEVI __device__ __forceinline__

DEVI float b2f(unsigned int u){ union{unsigned int i; float f;} c; c.i = u<<16; return c.f; }
DEVI unsigned short f2b(float f){
  union{float f; unsigned int i;} c; c.f = f;
  unsigned int r = c.i + 0x7fffu + ((c.i>>16)&1u);
  return (unsigned short)(r>>16);
}
DEVI unsigned int pack2(float a, float b){
  return (unsigned int)f2b(a) | ((unsigned int)f2b(b)<<16);
}
DEVI void unpack8(uint4 u, float* f){
  f[0]=b2f(u.x&0xffffu); f[1]=b2f(u.x>>16);
  f[2]=b2f(u.y&0xffffu); f[3]=b2f(u.y>>16);
  f[4]=b2f(u.z&0xffffu); f[5]=b2f(u.z>>16);
  f[6]=b2f(u.w&0xffffu); f[7]=b2f(u.w>>16);
}
DEVI f32x4 mfma16(bf16x8 a, bf16x8 b, f32x4 c){
  return __builtin_amdgcn_mfma_f32_16x16x32_bf16(a, b, c, 0, 0, 0);
}
DEVI f32x4 mfma16x16(bf16x4 a, bf16x4 b, f32x4 c){
#if __has_builtin(__builtin_amdgcn_mfma_f32_16x16x16bf16_1k)
  return __builtin_amdgcn_mfma_f32_16x16x16bf16_1k(a, b, c, 0, 0, 0);
#else
  f32x4 d = c;
  asm volatile("v_mfma_f32_16x16x16_bf16 %0, %1, %2, %0" : "+v"(d) : "v"(a), "v"(b));
  return d;
#endif
}
DEVI float gelu_fast(float u){
  const float y = 0.7978845608028654f*(u + 0.044715f*u*u*u);
  const float t = __expf(2.f*y);
  const float th = 1.f - 2.f/(t + 1.f);
  return 0.5f*u*(1.f + th);
}
// XOR swizzles
DEVI int swzA(int row, int byi){ return row*256 + (byi ^ ((row&7)<<4)); }      // rows x 128 bf16
DEVI int swzQ(int row, int byi){ return row*64  + (byi ^ (((row>>1)&3)<<4)); } // 64x32  bf16
DEVI int swzO(int row, int byc){ return row*512 + (byc ^ ((row&7)<<4) ^ (((byc>>7)&3)<<5)); } // 64x128 f32

// ---------------- K0: weights -> bf16 MFMA-fragment order + rpb expansion ----------------
__global__ void k_prep(const float* __restrict__ qkvw, const float* __restrict__ projw,
                       const float* __restrict__ w1,   const float* __restrict__ w2,
                       const float* __restrict__ rpbt,
                       ushort* __restrict__ qkvF, ushort* __restrict__ projF,
                       ushort* __restrict__ w1F,  ushort* __restrict__ w2F,
                       ushort* __restrict__ rpbE)
{
  const int t = blockIdx.x*256 + threadIdx.x;   // 0..16383
  const int l = t&63, fr = t>>6;                // frag id 0..255
  const int l15 = l&15, l4 = l>>4;
  { // rpbE[head][q][k] bf16
    const int head = t>>12, q = (t>>6)&63, k = t&63;
    const int di = (q>>3)-(k>>3)+7, dj = (q&7)-(k&7)+7;
    rpbE[t] = f2b(rpbt[(di*15+dj)*4 + head]);
  }
  { // w2F: 256 frags x 512B ; lane: w2[hid0+e][oc], e=0..3
    const int c = fr>>5, og = (fr>>2)&7, h = fr&3;
    const int oc = og*16 + l15, hid0 = c*64 + h*16 + l4*4;
    ushort* d = w2F + (size_t)fr*256 + l*4;
    #pragma unroll
    for(int e=0;e<4;e++) d[e] = f2b(w2[(size_t)(hid0+e)*128 + oc]);
  }
  if (fr < 128){ // w1F
    const int c = fr>>4, hg = (fr>>2)&3, kk = fr&3;
    const int hid = c*64 + hg*16 + l15, k0 = kk*32 + l4*8;
    ushort* d = w1F + (size_t)fr*512 + l*8;
    #pragma unroll
    for(int e=0;e<8;e++) d[e] = f2b(w1[(size_t)(k0+e)*512 + hid]);
  }
  if (fr < 96){ // qkvF: fr = (s3*8+g)*4+kk
    const int s3 = fr>>5, g = (fr>>2)&7, kk = fr&3;
    const int col = s3*128 + g*16 + l15, k0 = kk*32 + l4*8;
    ushort* d = qkvF + (size_t)fr*512 + l*8;
    #pragma unroll
    for(int e=0;e<8;e++) d[e] = f2b(qkvw[(size_t)(k0+e)*384 + col]);
  }
  if (fr < 32){ // projF
    const int g = fr>>2, kk = fr&3;
    const int col = g*16 + l15, k0 = kk*32 + l4*8;
    ushort* d = projF + (size_t)fr*512 + l*8;
    #pragma unroll
    for(int e=0;e<8;e++) d[e] = f2b(projw[(size_t)(k0+e)*128 + col]);
  }
}

// ---------------- K1: fused window attention (S^T, reg P/V) ----------------
__global__ __launch_bounds__(256,3) void k_attn(
    const float*  __restrict__ x,
    const float*  __restrict__ g1, const float* __restrict__ be1,
    const ushort* __restrict__ qkvF, const float* __restrict__ qkvb,
    const ushort* __restrict__ projF, const float* __restrict__ projb,
    const ushort* __restrict__ rpbE,
    ushort* __restrict__ x2w)
{
  __shared__ __align__(16) char smem[49152];
  const int tid  = threadIdx.x;
  const int wave = tid>>6, lane = tid&63;
  const int l15 = lane&15, l4 = lane>>4;
  const int wid = blockIdx.x;
  const int b   = wid>>6, wim = wid&63;
  const int wh  = wim>>3, wv = wim&7;

  char* const smA  = smem;                      // 16 KB: LN1 tile / attn-O
  char* const smQ  = smem + 16384 + wave*8192;  // 4 KB per head
  char* const smK  = smQ + 4096;                // 4 KB per head
  char* const smR  = smem + 16384;              // 32 KB fp32 proj restage (after heads dead)

  const f32x4 Z = {0.f,0.f,0.f,0.f};
  const int t_row = tid>>2;
  const int cg    = (tid&3)*32;
  const int ti_r = t_row>>3, tj_r = t_row&7;
  const int ho_r = (wh*8+ti_r+4)&63, wo_r = (wv*8+tj_r+4)&63;
  const size_t growbase = ((size_t)(b*4096 + ho_r*64 + wo_r))*128;

  { // ---- Phase 1: gather (roll -4,-4) + LN1 -> smA ----
    const float* src = x + growbase + cg;
    float v[32];
    #pragma unroll
    for(int q=0;q<8;q++){
      const float4 f4 = *(const float4*)(src + q*4);
      v[q*4+0]=f4.x; v[q*4+1]=f4.y; v[q*4+2]=f4.z; v[q*4+3]=f4.w;
    }
    float s=0.f, ss=0.f;
    #pragma unroll
    for(int e=0;e<32;e++){ s+=v[e]; ss+=v[e]*v[e]; }
    s += __shfl_xor(s,1); ss += __shfl_xor(ss,1);
    s += __shfl_xor(s,2); ss += __shfl_xor(ss,2);
    const float mean = s*(1.f/128.f);
    const float varv = fmaxf(ss*(1.f/128.f) - mean*mean, 0.f);
    const float rstd = rsqrtf(varv + 1e-5f);
    #pragma unroll
    for(int q=0;q<4;q++){
      const float4 ga = *(const float4*)(g1 +cg+q*8);
      const float4 gb = *(const float4*)(g1 +cg+q*8+4);
      const float4 ba = *(const float4*)(be1+cg+q*8);
      const float4 bb = *(const float4*)(be1+cg+q*8+4);
      const float* vp = v + q*8;
      uint4 pk;
      pk.x = pack2((vp[0]-mean)*rstd*ga.x+ba.x, (vp[1]-mean)*rstd*ga.y+ba.y);
      pk.y = pack2((vp[2]-mean)*rstd*ga.z+ba.z, (vp[3]-mean)*rstd*ga.w+ba.w);
      pk.z = pack2((vp[4]-mean)*rstd*gb.x+bb.x, (vp[5]-mean)*rstd*gb.y+bb.y);
      pk.w = pack2((vp[6]-mean)*rstd*gb.z+bb.z, (vp[7]-mean)*rstd*gb.w+bb.w);
      *(uint4*)(smA + swzA(t_row, cg*2 + q*16)) = pk;
    }
  }
  __syncthreads();

  const int headc = wave*32;
  bf16x4 Vf[4][2];   // V in registers: [token-group][d-group], PV B-frags

  { // ---- Phase 2: QKV. Q,K -> LDS (scaled Q); V packed to regs ----
    #pragma unroll
    for(int s3=0;s3<3;s3++){
      f32x4 acc[4][2];
      #pragma unroll
      for(int rt=0;rt<4;rt++){ acc[rt][0]=Z; acc[rt][1]=Z; }
      bf16x8 bfr[2][4];
      #pragma unroll
      for(int ct=0;ct<2;ct++)
        #pragma unroll
        for(int kk=0;kk<4;kk++)
          bfr[ct][kk] = *(const bf16x8*)(qkvF + (size_t)((s3*8 + wave*2 + ct)*4 + kk)*512 + lane*8);
      #pragma unroll
      for(int kk=0;kk<4;kk++){
        bf16x8 afr[4];
        #pragma unroll
        for(int rt=0;rt<4;rt++)
          afr[rt] = *(const bf16x8*)(smA + swzA(rt*16+l15, kk*64 + l4*16));
        #pragma unroll
        for(int rt=0;rt<4;rt++)
          #pragma unroll
          for(int ct=0;ct<2;ct++)
            acc[rt][ct] = mfma16(afr[rt], bfr[ct][kk], acc[rt][ct]);
      }
      #pragma unroll
      for(int ct=0;ct<2;ct++){
        const int hd = ct*16 + l15;
        const float bias = qkvb[s3*128 + headc + hd];
        if (s3==2){
          #pragma unroll
          for(int rt=0;rt<4;rt++){
            union { uint2 u; bf16x4 v; } cv;
            cv.u.x = pack2(acc[rt][ct][0]+bias, acc[rt][ct][1]+bias);
            cv.u.y = pack2(acc[rt][ct][2]+bias, acc[rt][ct][3]+bias);
            Vf[rt][ct] = cv.v;
          }
        } else {
          char* const dst = (s3==0) ? smQ : smK;
          const float sc = (s3==0) ? 0.17677669529663687f : 1.f;
          #pragma unroll
          for(int rt=0;rt<4;rt++){
            const int t0 = rt*16 + l4*4;
            #pragma unroll
            for(int j=0;j<4;j++)
              *(ushort*)(dst + swzQ(t0+j, hd*2)) = f2b((acc[rt][ct][j]+bias)*sc);
          }
        }
      }
    }
  }
  __syncthreads();  // all waves done reading smA (it becomes O below)

  // ---- Phase 3+4: S^T scores + rpb + mask + softmax + PV (all in registers) ----
  f32x4 O[4][2];
  #pragma unroll
  for(int rt=0;rt<4;rt++){ O[rt][0]=Z; O[rt][1]=Z; }
  {
    bf16x8 kfr[4];
    #pragma unroll
    for(int g=0; g<4; ++g)
      kfr[g] = *(const bf16x8*)(smK + swzQ(g*16+l15, l4*16));
    const bool edge = (wh==7) || (wv==7);
    #pragma unroll
    for(int rt=0; rt<4; ++rt){
      const bf16x8 qf = *(const bf16x8*)(smQ + swzQ(rt*16+l15, l4*16));
      f32x4 S[4];
      #pragma unroll
      for(int g=0; g<4; ++g)
        S[g] = mfma16(kfr[g], qf, Z);     // S^T: col=q(l15), row=k(l4*4+j)
      const int q = rt*16 + l15;
      int regq = 0;
      if (edge){
        const int qi=q>>3, qj=q&7;
        regq = ((wh<7)?0:((qi<4)?1:2))*3 + ((wv<7)?0:((qj<4)?1:2));
      }
      const ushort* rbase = rpbE + wave*4096 + q*64 + l4*4;
      #pragma unroll
      for(int g=0; g<4; ++g){
        const u16x4 rb = *(const u16x4*)(rbase + g*16);
        #pragma unroll
        for(int j=0;j<4;j++){
          float add = b2f(rb[j]);
          if (edge){
            const int k = g*16 + l4*4 + j;
            const int ki=k>>3, kj=k&7;
            const int regk = ((wh<7)?0:((ki<4)?1:2))*3 + ((wv<7)?0:((kj<4)?1:2));
            if (regk != regq) add -= 100.f;
          }
          S[g][j] += add;
        }
      }
      float mx = -1e30f;
      #pragma unroll
      for(int g=0;g<4;g++)
        #pragma unroll
        for(int j=0;j<4;j++) mx = fmaxf(mx, S[g][j]);
      mx = fmaxf(mx, __shfl_xor(mx,16));
      mx = fmaxf(mx, __shfl_xor(mx,32));
      float sm = 0.f;
      #pragma unroll
      for(int g=0;g<4;g++)
        #pragma unroll
        for(int j=0;j<4;j++){ const float e = __expf(S[g][j]-mx); S[g][j]=e; sm+=e; }
      sm += __shfl_xor(sm,16);
      sm += __shfl_xor(sm,32);
      const float inv = 1.f/sm;
      #pragma unroll
      for(int g=0;g<4;g++){
        union { uint2 u; bf16x4 v; } cv;
        cv.u.x = pack2(S[g][0]*inv, S[g][1]*inv);
        cv.u.y = pack2(S[g][2]*inv, S[g][3]*inv);
        #pragma unroll
        for(int cvi=0;cvi<2;cvi++)
          O[rt][cvi] = mfma16x16(cv.v, Vf[g][cvi], O[rt][cvi]);
      }
    }
    // O store: lane d=l15, token=rt*16+l4*4+j
    #pragma unroll
    for(int rt=0;rt<4;rt++)
      #pragma unroll
      for(int cvi=0;cvi<2;cvi++)
        #pragma unroll
        for(int j=0;j<4;j++)
          *(ushort*)(smA + swzA(rt*16+l4*4+j, (headc + cvi*16 + l15)*2)) = f2b(O[rt][cvi][j]);
  }
  __syncthreads();   // all O written; Q/K areas now dead

  { // ---- Phase 5: proj + bias -> smR (fp32, swzO) ----
    f32x4 PR[4][2];
    #pragma unroll
    for(int rt=0;rt<4;rt++){ PR[rt][0]=Z; PR[rt][1]=Z; }
    bf16x8 pb[2][4];
    #pragma unroll
    for(int ct=0;ct<2;ct++)
      #pragma unroll
      for(int kk=0;kk<4;kk++)
        pb[ct][kk] = *(const bf16x8*)(projF + (size_t)((wave*2+ct)*4 + kk)*512 + lane*8);
    #pragma unroll
    for(int kk=0;kk<4;kk++){
      bf16x8 afr[4];
      #pragma unroll
      for(int rt=0;rt<4;rt++)
        afr[rt] = *(const bf16x8*)(smA + swzA(rt*16+l15, kk*64 + l4*16));
      #pragma unroll
      for(int rt=0;rt<4;rt++)
        #pragma unroll
        for(int ct=0;ct<2;ct++)
          PR[rt][ct] = mfma16(afr[rt], pb[ct][kk], PR[rt][ct]);
    }
    #pragma unroll
    for(int ct=0;ct<2;ct++){
      const int col = headc + ct*16 + l15;
      const float bias = projb[col];
      #pragma unroll
      for(int rt=0;rt<4;rt++)
        #pragma unroll
        for(int j=0;j<4;j++)
          *(float*)(smR + swzO(rt*16+l4*4+j, col*4)) = PR[rt][ct][j] + bias;
    }
  }
  __syncthreads();

  { // ---- Phase 6: x2 = x(re-read, coalesced) + projout; uint4 stores ----
    const float* xsrc = x + growbase + cg;
    ushort* drow = x2w + ((size_t)(wid*64 + t_row))*128 + cg;
    #pragma unroll
    for(int q=0;q<4;q++){
      const f32x4 oa = *(const f32x4*)(smR + swzO(t_row, (cg+q*8  )*4));
      const f32x4 ob = *(const f32x4*)(smR + swzO(t_row, (cg+q*8+4)*4));
      const float4 xa = *(const float4*)(xsrc + q*8);
      const float4 xb = *(const float4*)(xsrc + q*8+4);
      uint4 pk;
      pk.x = pack2(oa[0]+xa.x, oa[1]+xa.y);
      pk.y = pack2(oa[2]+xa.z, oa[3]+xa.w);
      pk.z = pack2(ob[0]+xb.x, ob[1]+xb.y);
      pk.w = pack2(ob[2]+xb.z, ob[3]+xb.w);
      *(uint4*)(drow + q*8) = pk;
    }
  }
}

// ---------------- K2: MLP (unchanged from R6) ----------------
__global__ __launch_bounds__(512,1) void k_mlp2(
    const ushort* __restrict__ x2w,
    const float* __restrict__ g2, const float* __restrict__ be2,
    const ushort* __restrict__ w1F, const float* __restrict__ bb1,
    const ushort* __restrict__ w2F, const float* __restrict__ bb2,
    float* __restrict__ outp)
{
  extern __shared__ __align__(16) char smem[];
  char* const smX  = smem;            // 64 KB
  char* const smW0 = smem + 65536;    // 32 KB
  char* const smW1 = smem + 98304;    // 32 KB
  const int tid  = threadIdx.x;
  const int wave = tid>>6, lane = tid&63;
  const int l15 = lane&15, l4 = lane>>4;
  const int gblk = blockIdx.x;
  const f32x4 Z = {0.f,0.f,0.f,0.f};

  const ushort* const wsrc = (tid & 256) ? w2F : w1F;
  const int soff = (tid & 255) * 32;
  const int loff = ((tid & 256) ? 16384 : 0) + (tid & 255)*64;
  uint4 stg0, stg1, stg2, stg3;
  {
    const uint4* p = (const uint4*)(wsrc + soff);
    stg0 = p[0]; stg1 = p[1]; stg2 = p[2]; stg3 = p[3];
  }

  {
    const int sub = tid>>2;
    const int cg  = (tid&3)*32;
    #pragma unroll
    for(int p=0;p<2;++p){
      const int tk = p*128 + sub;
      const ushort* src = x2w + ((size_t)(gblk*256 + tk))*128 + cg;
      float v[32];
      unpack8(*(const uint4*)(src   ), v   );
      unpack8(*(const uint4*)(src+ 8), v+ 8);
      unpack8(*(const uint4*)(src+16), v+16);
      unpack8(*(const uint4*)(src+24), v+24);
      float s=0.f, ss=0.f;
      #pragma unroll
      for(int e=0;e<32;e++){ s+=v[e]; ss+=v[e]*v[e]; }
      s += __shfl_xor(s,1); ss += __shfl_xor(ss,1);
      s += __shfl_xor(s,2); ss += __shfl_xor(ss,2);
      const float mean = s*(1.f/128.f);
      const float varv = fmaxf(ss*(1.f/128.f) - mean*mean, 0.f);
      const float rstd = rsqrtf(varv + 1e-5f);
      #pragma unroll
      for(int q=0;q<4;q++){
        const float4 ga = *(const float4*)(g2 +cg+q*8);
        const float4 gb = *(const float4*)(g2 +cg+q*8+4);
        const float4 ba = *(const float4*)(be2+cg+q*8);
        const float4 bb = *(const float4*)(be2+cg+q*8+4);
        const float* vp = v + q*8;
        uint4 pk;
        pk.x = pack2((vp[0]-mean)*rstd*ga.x+ba.x, (vp[1]-mean)*rstd*ga.y+ba.y);
        pk.y = pack2((vp[2]-mean)*rstd*ga.z+ba.z, (vp[3]-mean)*rstd*ga.w+ba.w);
        pk.z = pack2((vp[4]-mean)*rstd*gb.x+bb.x, (vp[5]-mean)*rstd*gb.y+bb.y);
        pk.w = pack2((vp[6]-mean)*rstd*gb.z+bb.z, (vp[7]-mean)*rstd*gb.w+bb.w);
        *(uint4*)(smX + swzA(tk, cg*2 + q*16)) = pk;
      }
    }
  }
  {
    uint4* d = (uint4*)(smW0 + loff);
    d[0]=stg0; d[1]=stg1; d[2]=stg2; d[3]=stg3;
  }
  __syncthreads();

  f32x4 OA[8][2];
  #pragma unroll
  for(int ocg=0;ocg<8;++ocg){ OA[ocg][0]=Z; OA[ocg][1]=Z; }

  for (int c=0; c<8; ++c){
    char* const buf = (c&1) ? smW1 : smW0;
    if (c<7){
      const uint4* p = (const uint4*)(wsrc + (size_t)(c+1)*8192 + soff);
      stg0 = p[0]; stg1 = p[1]; stg2 = p[2]; stg3 = p[3];
    }
    const int hidb = c*64;
    #pragma unroll
    for (int tokg=0; tokg<2; ++tokg){
      const int trow = wave*32 + tokg*16 + l15;
      bf16x8 xf[4];
      #pragma unroll
      for(int kk=0;kk<4;++kk)
        xf[kk] = *(const bf16x8*)(smX + swzA(trow, kk*64 + l4*16));
      f32x4 acc1[4] = {Z,Z,Z,Z};
      #pragma unroll
      for(int hg=0; hg<4; ++hg)
        #pragma unroll
        for(int kk=0; kk<4; ++kk){
          const bf16x8 wf = *(const bf16x8*)(buf + (hg*4+kk)*1024 + lane*16);
          acc1[hg] = mfma16(wf, xf[kk], acc1[hg]);
        }
      bf16x4 Hf[4];
      #pragma unroll
      for(int hg=0; hg<4; ++hg){
        const float4 b4 = *(const float4*)(bb1 + hidb + hg*16 + l4*4);
        bf16x4 hv;
        hv[0] = (short)f2b(gelu_fast(acc1[hg][0]+b4.x));
        hv[1] = (short)f2b(gelu_fast(acc1[hg][1]+b4.y));
        hv[2] = (short)f2b(gelu_fast(acc1[hg][2]+b4.z));
        hv[3] = (short)f2b(gelu_fast(acc1[hg][3]+b4.w));
        Hf[hg] = hv;
      }
      #pragma unroll
      for(int ocg=0; ocg<8; ++ocg)
        #pragma unroll
        for(int hg=0; hg<4; ++hg){
          const bf16x4 w2f = *(const bf16x4*)(buf + 16384 + (ocg*4+hg)*512 + lane*8);
          OA[ocg][tokg] = mfma16x16(w2f, Hf[hg], OA[ocg][tokg]);
        }
    }
    if (c<7){
      char* const nbuf = (c&1) ? smW0 : smW1;
      uint4* d = (uint4*)(nbuf + loff);
      d[0]=stg0; d[1]=stg1; d[2]=stg2; d[3]=stg3;
    }
    __syncthreads();
  }

  {
    const int sub = tid>>2;
    const int cg  = (tid&3)*32;
    #pragma unroll
    for(int p=0;p<2;++p){
      const int tk = p*128 + sub;
      const uint4* src = (const uint4*)(x2w + ((size_t)(gblk*256 + tk))*128 + cg);
      #pragma unroll
      for(int q=0;q<4;q++) *(uint4*)(smX + swzA(tk, cg*2 + q*16)) = src[q];
    }
  }
  __syncthreads();
  #pragma unroll
  for(int tokg=0; tokg<2; ++tokg){
    const int tk  = wave*32 + tokg*16 + l15;
    const int wid = gblk*4 + (tk>>6);
    const int n   = tk & 63;
    const int bb  = wid>>6, wim = wid&63;
    const int wh  = wim>>3, wv = wim&7;
    const int ti  = n>>3,  tj = n&7;
    const int ho  = (wh*8+ti+4)&63, wo = (wv*8+tj+4)&63;
    float* const drow = outp + ((size_t)(bb*4096 + ho*64 + wo))*128;
    #pragma unroll
    for(int ocg=0; ocg<8; ++ocg){
      const int oc = ocg*16 + l4*4;
      const float4 b4 = *(const float4*)(bb2 + oc);
      const u16x4 xr = *(const u16x4*)(smX + swzA(tk, oc*2));
      f32x4 r = OA[ocg][tokg];
      r[0] += b4.x + b2f(xr[0]);
      r[1] += b4.y + b2f(xr[1]);
      r[2] += b4.z + b2f(xr[2]);
      r[3] += b4.w + b2f(xr[3]);
      __builtin_nontemporal_store(r, (f32x4*)(drow + oc));
    }
  }
}

extern "C" void kernel_launch(void* const* d_in, const int* in_sizes, int n_in,
                              void* d_out, int out_size, void* d_ws, size_t ws_size,
                              hipStream_t stream) {
  (void)in_sizes; (void)n_in; (void)out_size; (void)ws_size;
  const float* x     = (const float*)d_in[0];
  const float* n1g   = (const float*)d_in[1];
  const float* n1b   = (const float*)d_in[2];
  const float* qkvw  = (const float*)d_in[3];
  const float* qkvb  = (const float*)d_in[4];
  const float* projw = (const float*)d_in[5];
  const float* projb = (const float*)d_in[6];
  const float* rpbt  = (const float*)d_in[7];
  const float* n2g   = (const float*)d_in[8];
  const float* n2b   = (const float*)d_in[9];
  const float* w1    = (const float*)d_in[10];
  const float* b1    = (const float*)d_in[11];
  const float* w2    = (const float*)d_in[12];
  const float* b2    = (const float*)d_in[13];
  float* outp = (float*)d_out;

  ushort* ws    = (ushort*)d_ws;
  ushort* x2w   = ws;                  // 16,777,216 bf16
  ushort* qkvF  = ws + 16777216;       // 49152
  ushort* projF = qkvF + 49152;        // 16384
  ushort* w1F   = projF + 16384;       // 65536
  ushort* w2F   = w1F + 65536;         // 65536
  ushort* rpbE  = w2F + 65536;         // 16384

  k_prep<<<64, 256, 0, stream>>>(qkvw, projw, w1, w2, rpbt, qkvF, projF, w1F, w2F, rpbE);
  k_attn<<<2048, 256, 0, stream>>>(x, n1g, n1b, qkvF, qkvb, projF, projb, rpbE, x2w);
  k_mlp2<<<512, 512, 131072, stream>>>(x2w, n2g, n2b, w1F, b1, w2F, b2, outp);
}